// Round 1
// baseline (363.052 us; speedup 1.0000x reference)
//
#include <hip/hip_runtime.h>
#include <hip/hip_bf16.h>

#define NBATCH 256
#define NNODES 512
#define DIM    128
#define NTOT   (NBATCH*NNODES)   // 131072
#define NEDGE  (NTOT*8)          // 1048576
#define EPB    130816            // NNODES*(NNODES-1)/2
#define CAP    48

typedef __attribute__((ext_vector_type(8))) short  short8;
typedef __attribute__((ext_vector_type(4))) float  f32x4;

__device__ __forceinline__ unsigned short f2bf(float f){
  unsigned u = __builtin_bit_cast(unsigned, f);
  unsigned r = u + 0x7FFFu + ((u >> 16) & 1u);   // RNE
  return (unsigned short)(r >> 16);
}

// ---------------- prep: embW1 = emb @ gin_W1 (fp32, 512x128) ----------------
__global__ __launch_bounds__(128) void k_embw1(const float* __restrict__ emb,
                                               const float* __restrict__ W1,
                                               float* __restrict__ embW1){
  const int r = blockIdx.x, c = threadIdx.x;
  __shared__ float er[DIM];
  er[c] = emb[r*DIM + c];
  __syncthreads();
  float acc = 0.f;
  #pragma unroll 8
  for (int k = 0; k < DIM; ++k) acc = fmaf(er[k], W1[k*DIM + c], acc);
  embW1[r*DIM + c] = acc;
}

// ---------------- prep: 3 weights -> bf16, transposed [n][k] ----------------
__global__ __launch_bounds__(256) void k_cvtT(const float* __restrict__ W2,
                                              const float* __restrict__ P1,
                                              const float* __restrict__ P2,
                                              unsigned short* __restrict__ dst){
  int idx = blockIdx.x*256 + threadIdx.x;          // 49152 total
  int which = idx >> 14, rem = idx & 16383, k = rem >> 7, n = rem & 127;
  const float* src = (which == 0) ? W2 : ((which == 1) ? P1 : P2);
  dst[which*16384 + n*DIM + k] = f2bf(src[k*DIM + n]);
}

// ---------------- edge scatter into capped per-node slots ----------------
__global__ __launch_bounds__(256) void k_edges(const int* __restrict__ ei,
                                               const int* __restrict__ nf,
                                               int* __restrict__ cnt,
                                               unsigned short* __restrict__ slots){
  int e = blockIdx.x*256 + threadIdx.x;
  int s = ei[e];
  int d = ei[NEDGE + e];
  int v = nf[s];
  int pos = atomicAdd(&cnt[d], 1);
  if (pos < CAP) slots[(size_t)d*CAP + pos] = (unsigned short)v;
}

// ---------------- fused GIN + post MLP + final LN ----------------
// 1024 blocks x 512 thr; each block: 128 node rows.
__global__ __launch_bounds__(512) void k_gin(
    const float* __restrict__ embW1, const int* __restrict__ nf,
    const int* __restrict__ cnt, const unsigned short* __restrict__ slots,
    const float* __restrict__ b1,  const float* __restrict__ g1, const float* __restrict__ be1,
    const unsigned short* __restrict__ wbf,   // [3][128n][128k] bf16 transposed
    const float* __restrict__ b2,  const float* __restrict__ pb1, const float* __restrict__ pb2,
    const float* __restrict__ ng,  const float* __restrict__ nbv,
    unsigned short* __restrict__ xbf, float* __restrict__ gsum)
{
  __shared__ unsigned short act[128][136];   // +8 pad: kills the D=128 bank conflict
  __shared__ float gpart[8][128];
  const int tid   = threadIdx.x;
  const int nbase = blockIdx.x * 128;

  // -------- gather phase: t = b1 + sum(embW1 rows); LN; relu; -> act (bf16)
  {
    const int r = tid >> 2, part = tid & 3;
    const int node = nbase + r;
    float4 a[8];
    {
      const int self = nf[node];
      const float4* p = (const float4*)(embW1 + (size_t)self*DIM + part*32);
      #pragma unroll
      for (int q = 0; q < 8; ++q) a[q] = p[q];
    }
    int m = cnt[node]; if (m > CAP) m = CAP;
    const unsigned short* sl = slots + (size_t)node*CAP;
    for (int e = 0; e < m; ++e) {
      const float4* p = (const float4*)(embW1 + (size_t)sl[e]*DIM + part*32);
      #pragma unroll
      for (int q = 0; q < 8; ++q) {
        a[q].x += p[q].x; a[q].y += p[q].y; a[q].z += p[q].z; a[q].w += p[q].w;
      }
    }
    {
      const float4* bp = (const float4*)(b1 + part*32);
      #pragma unroll
      for (int q = 0; q < 8; ++q) {
        a[q].x += bp[q].x; a[q].y += bp[q].y; a[q].z += bp[q].z; a[q].w += bp[q].w;
      }
    }
    float s = 0.f, qs = 0.f;
    #pragma unroll
    for (int q = 0; q < 8; ++q) {
      s  += a[q].x + a[q].y + a[q].z + a[q].w;
      qs += a[q].x*a[q].x + a[q].y*a[q].y + a[q].z*a[q].z + a[q].w*a[q].w;
    }
    s  += __shfl_xor(s, 1, 64);  s  += __shfl_xor(s, 2, 64);
    qs += __shfl_xor(qs, 1, 64); qs += __shfl_xor(qs, 2, 64);
    const float mean = s * (1.f/128.f);
    const float var  = qs * (1.f/128.f) - mean*mean;
    const float rs   = rsqrtf(var + 1e-5f);
    #pragma unroll
    for (int q = 0; q < 8; ++q) {
      float4 gv = ((const float4*)g1 )[part*8 + q];
      float4 bv = ((const float4*)be1)[part*8 + q];
      float v0 = fmaxf((a[q].x - mean)*rs*gv.x + bv.x, 0.f);
      float v1 = fmaxf((a[q].y - mean)*rs*gv.y + bv.y, 0.f);
      float v2 = fmaxf((a[q].z - mean)*rs*gv.z + bv.z, 0.f);
      float v3 = fmaxf((a[q].w - mean)*rs*gv.w + bv.w, 0.f);
      uint2 pk;
      pk.x = (unsigned)f2bf(v0) | ((unsigned)f2bf(v1) << 16);
      pk.y = (unsigned)f2bf(v2) | ((unsigned)f2bf(v3) << 16);
      *(uint2*)&act[r][part*32 + q*4] = pk;
    }
  }
  __syncthreads();

  const int wave = tid >> 6, lane = tid & 63;
  const int l15 = lane & 15, lg = lane >> 4;
  const int arow = wave*16 + l15;

  for (int s = 0; s < 3; ++s) {
    f32x4 acc[8];
    #pragma unroll
    for (int n = 0; n < 8; ++n) acc[n] = (f32x4){0.f,0.f,0.f,0.f};
    const unsigned short* w = wbf + s*16384;
    #pragma unroll
    for (int ks = 0; ks < 4; ++ks) {
      const int k0 = ks*32 + lg*8;
      short8 af = *(const short8*)&act[arow][k0];
      #pragma unroll
      for (int n = 0; n < 8; ++n) {
        short8 bf = *(const short8*)(w + (size_t)(n*16 + l15)*DIM + k0);
        acc[n] = __builtin_amdgcn_mfma_f32_16x16x32_bf16(af, bf, acc[n], 0, 0, 0);
      }
    }
    __syncthreads();   // all reads of act done before overwrite

    if (s < 2) {
      const float* bias = (s == 0) ? b2 : pb1;
      #pragma unroll
      for (int n = 0; n < 8; ++n) {
        const float bb = bias[n*16 + l15];
        #pragma unroll
        for (int r = 0; r < 4; ++r) {
          float v = acc[n][r] + bb;
          if (s == 1) v = fmaxf(v, 0.f);
          act[wave*16 + lg*4 + r][n*16 + l15] = f2bf(v);
        }
      }
      __syncthreads();
    } else {
      // final LayerNorm + write x' (bf16) + per-graph column sums
      float sr[4] = {0,0,0,0}, qr[4] = {0,0,0,0};
      #pragma unroll
      for (int n = 0; n < 8; ++n) {
        const float bb = pb2[n*16 + l15];
        #pragma unroll
        for (int r = 0; r < 4; ++r) {
          float v = acc[n][r] + bb; acc[n][r] = v;
          sr[r] += v; qr[r] += v*v;
        }
      }
      #pragma unroll
      for (int r = 0; r < 4; ++r) {
        #pragma unroll
        for (int msk = 1; msk < 16; msk <<= 1) {
          sr[r] += __shfl_xor(sr[r], msk, 64);
          qr[r] += __shfl_xor(qr[r], msk, 64);
        }
      }
      float mean[4], rs[4];
      #pragma unroll
      for (int r = 0; r < 4; ++r) {
        mean[r] = sr[r]*(1.f/128.f);
        float var = qr[r]*(1.f/128.f) - mean[r]*mean[r];
        rs[r] = rsqrtf(var + 1e-5f);
      }
      float pc[8];
      #pragma unroll
      for (int n = 0; n < 8; ++n) pc[n] = 0.f;
      #pragma unroll
      for (int n = 0; n < 8; ++n) {
        const int col = n*16 + l15;
        const float gc = ng[col], bc = nbv[col];
        #pragma unroll
        for (int r = 0; r < 4; ++r) {
          float xo = (acc[n][r] - mean[r])*rs[r]*gc + bc;
          xbf[(size_t)(nbase + wave*16 + lg*4 + r)*DIM + col] = f2bf(xo);
          pc[n] += xo;
        }
      }
      #pragma unroll
      for (int n = 0; n < 8; ++n) {
        pc[n] += __shfl_xor(pc[n], 16, 64);
        pc[n] += __shfl_xor(pc[n], 32, 64);
      }
      if (lane < 16) {
        #pragma unroll
        for (int n = 0; n < 8; ++n) gpart[wave][n*16 + lane] = pc[n];
      }
      __syncthreads();
      if (tid < 128) {
        float s2 = 0.f;
        #pragma unroll
        for (int wv = 0; wv < 8; ++wv) s2 += gpart[wv][tid];
        atomicAdd(&gsum[(blockIdx.x >> 2)*DIM + tid], s2);
      }
    }
  }
}

// ---------------- means -> exit MLP -> action_type ----------------
__global__ __launch_bounds__(128) void k_exit(const float* __restrict__ gsum,
    const float* __restrict__ W1, const float* __restrict__ b1,
    const float* __restrict__ g,  const float* __restrict__ be,
    const float* __restrict__ W2, const float* __restrict__ b2,
    float* __restrict__ out)
{
  const int gi = blockIdx.x, tid = threadIdx.x;
  __shared__ float mrow[DIM];
  __shared__ float red[4];
  __shared__ float red2[2];
  mrow[tid] = gsum[gi*DIM + tid] * (1.f/512.f);
  __syncthreads();
  float u = b1[tid];
  #pragma unroll 8
  for (int k = 0; k < DIM; ++k) u = fmaf(mrow[k], W1[k*DIM + tid], u);
  float s = u, q = u*u;
  #pragma unroll
  for (int m = 1; m < 64; m <<= 1) { s += __shfl_xor(s, m, 64); q += __shfl_xor(q, m, 64); }
  const int wv = tid >> 6;
  if ((tid & 63) == 0) { red[wv*2] = s; red[wv*2+1] = q; }
  __syncthreads();
  const float S = red[0] + red[2], Q = red[1] + red[3];
  const float mean = S*(1.f/128.f);
  const float var  = Q*(1.f/128.f) - mean*mean;
  float a = fmaxf((u - mean)*rsqrtf(var + 1e-5f)*g[tid] + be[tid], 0.f);
  float p = a * W2[tid];
  #pragma unroll
  for (int m = 1; m < 64; m <<= 1) p += __shfl_xor(p, m, 64);
  if ((tid & 63) == 0) red2[wv] = p;
  __syncthreads();
  if (tid == 0) {
    float e = red2[0] + red2[1] + b2[0];
    out[gi*3 + 1] = 1.f - e;
    out[gi*3 + 2] = e;
  }
}

// ---------------- batched X X^T, packed upper-triangular write ----------------
__global__ __launch_bounds__(256) void k_scores(const unsigned short* __restrict__ xbf,
                                                float* __restrict__ out)
{
  static const int TI[10] = {0,0,0,0,1,1,1,2,2,3};
  static const int TJ[10] = {0,1,2,3,1,2,3,2,3,3};
  const int b = blockIdx.x / 10, p = blockIdx.x % 10;
  const int ti = TI[p], tj = TJ[p];
  const int tid = threadIdx.x;
  const int wave = tid >> 6, lane = tid & 63;
  const int l15 = lane & 15, lg = lane >> 4;
  const unsigned short* Xb = xbf + (size_t)b*NNODES*DIM;

  f32x4 acc0[8], acc1[8];
  #pragma unroll
  for (int n = 0; n < 8; ++n) { acc0[n] = (f32x4){0,0,0,0}; acc1[n] = (f32x4){0,0,0,0}; }

  #pragma unroll
  for (int ks = 0; ks < 4; ++ks) {
    const int k0 = ks*32 + lg*8;
    short8 a0 = *(const short8*)&Xb[(size_t)(ti*128 + wave*32 +  0 + l15)*DIM + k0];
    short8 a1 = *(const short8*)&Xb[(size_t)(ti*128 + wave*32 + 16 + l15)*DIM + k0];
    #pragma unroll
    for (int n = 0; n < 8; ++n) {
      short8 bf = *(const short8*)&Xb[(size_t)(tj*128 + n*16 + l15)*DIM + k0];
      acc0[n] = __builtin_amdgcn_mfma_f32_16x16x32_bf16(a0, bf, acc0[n], 0, 0, 0);
      acc1[n] = __builtin_amdgcn_mfma_f32_16x16x32_bf16(a1, bf, acc1[n], 0, 0, 0);
    }
  }

  const float scale = 0.08838834764831845f;   // 1/sqrt(128)
  float* ea = out + 3072 + (size_t)b*EPB;
  #pragma unroll
  for (int m = 0; m < 2; ++m) {
    #pragma unroll
    for (int n = 0; n < 8; ++n) {
      const int gj = tj*128 + n*16 + l15;
      #pragma unroll
      for (int r = 0; r < 4; ++r) {
        const int gi = ti*128 + wave*32 + m*16 + lg*4 + r;
        if (gi < gj) {
          const int rowbase = gi*511 - (gi*(gi-1))/2 - gi - 1;
          const float v = (m == 0) ? acc0[n][r] : acc1[n][r];
          ea[rowbase + gj] = v * scale;
        }
      }
    }
  }
}

extern "C" void kernel_launch(void* const* d_in, const int* in_sizes, int n_in,
                              void* d_out, int out_size, void* d_ws, size_t ws_size,
                              hipStream_t stream) {
  const int*   nf   = (const int*)d_in[0];
  const int*   ei   = (const int*)d_in[1];
  const float* emb  = (const float*)d_in[3];
  const float* gW1  = (const float*)d_in[4];
  const float* gb1  = (const float*)d_in[5];
  const float* gg1  = (const float*)d_in[6];
  const float* gbe1 = (const float*)d_in[7];
  const float* gW2  = (const float*)d_in[8];
  const float* gb2  = (const float*)d_in[9];
  const float* pW1  = (const float*)d_in[10];
  const float* pb1  = (const float*)d_in[11];
  const float* pW2  = (const float*)d_in[12];
  const float* pb2  = (const float*)d_in[13];
  const float* ng   = (const float*)d_in[14];
  const float* nb   = (const float*)d_in[15];
  const float* eW1  = (const float*)d_in[16];
  const float* eb1  = (const float*)d_in[17];
  const float* eg   = (const float*)d_in[18];
  const float* ebe  = (const float*)d_in[19];
  const float* eW2  = (const float*)d_in[20];
  const float* eb2  = (const float*)d_in[21];
  float* out = (float*)d_out;

  char* ws = (char*)d_ws;
  float*          embW1 = (float*)ws;                          // 262144 B
  unsigned short* wbf   = (unsigned short*)(ws + 262144);      // 98304 B
  int*            cnt   = (int*)(ws + 360448);                 // 524288 B
  unsigned short* slots = (unsigned short*)(ws + 884736);      // 12582912 B
  unsigned short* xbf   = (unsigned short*)(ws + 13467648);    // 33554432 B
  float*          gsum  = (float*)(ws + 47022080);             // 131072 B
  if (ws_size < 47153152) return;                              // need ~45 MB

  hipMemsetAsync(cnt, 0, NTOT*sizeof(int), stream);
  hipMemsetAsync(gsum, 0, NBATCH*DIM*sizeof(float), stream);
  hipMemsetAsync(out, 0, 3072*sizeof(float), stream);          // action_type/edge_class/node_class zeros

  k_embw1 <<<512, 128, 0, stream>>>(emb, gW1, embW1);
  k_cvtT  <<<192, 256, 0, stream>>>(gW2, pW1, pW2, wbf);
  k_edges <<<NEDGE/256, 256, 0, stream>>>(ei, nf, cnt, slots);
  k_gin   <<<1024, 512, 0, stream>>>(embW1, nf, cnt, slots, gb1, gg1, gbe1,
                                     wbf, gb2, pb1, pb2, ng, nb, xbf, gsum);
  k_exit  <<<256, 128, 0, stream>>>(gsum, eW1, eb1, eg, ebe, eW2, eb2, out);
  k_scores<<<2560, 256, 0, stream>>>(xbf, out);
}

// Round 2
// 271.726 us; speedup vs baseline: 1.3361x; 1.3361x over previous
//
#include <hip/hip_runtime.h>
#include <hip/hip_bf16.h>

#define NBATCH 256
#define NNODES 512
#define DIM    128
#define NTOT   (NBATCH*NNODES)   // 131072
#define NEDGE  (NTOT*8)          // 1048576
#define EPB    130816            // NNODES*(NNODES-1)/2
#define CAP    48

typedef __attribute__((ext_vector_type(8))) short  short8;
typedef __attribute__((ext_vector_type(4))) float  f32x4;

__device__ __forceinline__ unsigned short f2bf(float f){
  unsigned u = __builtin_bit_cast(unsigned, f);
  unsigned r = u + 0x7FFFu + ((u >> 16) & 1u);   // RNE
  return (unsigned short)(r >> 16);
}

// ---------------- prep: embW1 = emb @ gin_W1 (fp32, 512x128) ----------------
__global__ __launch_bounds__(128) void k_embw1(const float* __restrict__ emb,
                                               const float* __restrict__ W1,
                                               float* __restrict__ embW1){
  const int r = blockIdx.x, c = threadIdx.x;
  __shared__ float er[DIM];
  er[c] = emb[r*DIM + c];
  __syncthreads();
  float acc = 0.f;
  #pragma unroll 8
  for (int k = 0; k < DIM; ++k) acc = fmaf(er[k], W1[k*DIM + c], acc);
  embW1[r*DIM + c] = acc;
}

// ------- prep: 3 weights -> bf16 in MFMA B-frag order [s][ks][n][lane][j] ----
// element (s,ks,n,lane=lg*16+l15,j) = W_s[k][c], k=ks*32+lg*8+j, c=n*16+l15
__global__ __launch_bounds__(256) void k_cvtT(const float* __restrict__ W2,
                                              const float* __restrict__ P1,
                                              const float* __restrict__ P2,
                                              unsigned short* __restrict__ dst){
  int idx = blockIdx.x*256 + threadIdx.x;          // 49152 total
  int s = idx >> 14, rem = idx & 16383;
  int ks = rem >> 12, n = (rem >> 9) & 7, lane = (rem >> 3) & 63, j = rem & 7;
  int lg = lane >> 4, l15 = lane & 15;
  int k = ks*32 + lg*8 + j, c = n*16 + l15;
  const float* src = (s == 0) ? W2 : ((s == 1) ? P1 : P2);
  dst[idx] = f2bf(src[k*DIM + c]);
}

// ---------------- edge scatter into capped per-node slots ----------------
__global__ __launch_bounds__(256) void k_edges(const int* __restrict__ ei,
                                               const int* __restrict__ nf,
                                               int* __restrict__ cnt,
                                               unsigned short* __restrict__ slots){
  int e = blockIdx.x*256 + threadIdx.x;
  int s = ei[e];
  int d = ei[NEDGE + e];
  int v = nf[s];
  int pos = atomicAdd(&cnt[d], 1);
  if (pos < CAP) slots[(size_t)d*CAP + pos] = (unsigned short)v;
}

// ---------------- fused GIN + post MLP + final LN ----------------
// 2048 blocks x 256 thr; each block: 64 node rows.
__global__ __launch_bounds__(256, 4) void k_gin(
    const float* __restrict__ embW1, const int* __restrict__ nf,
    const int* __restrict__ cnt, const unsigned short* __restrict__ slots,
    const float* __restrict__ b1,  const float* __restrict__ g1, const float* __restrict__ be1,
    const unsigned short* __restrict__ wswz,   // [3][4ks][8n][64lane][8j] bf16 frag-order
    const float* __restrict__ b2,  const float* __restrict__ pb1, const float* __restrict__ pb2,
    const float* __restrict__ ng,  const float* __restrict__ nbv,
    unsigned short* __restrict__ xswz, float* __restrict__ gsum)
{
  __shared__ unsigned short act[64][136];   // +8 pad kills D=128 bank conflicts
  __shared__ float gpart[4][128];
  const int tid   = threadIdx.x;
  const int nbase = blockIdx.x * 64;

  // -------- gather: t = b1 + sum(embW1 rows); LN; relu; -> act (bf16)
  {
    const int r = tid >> 2, part = tid & 3;
    const int node = nbase + r;
    float4 a0,a1,a2,a3,a4,a5,a6,a7;
    {
      const float4* bp = (const float4*)(b1 + part*32);
      a0=bp[0]; a1=bp[1]; a2=bp[2]; a3=bp[3]; a4=bp[4]; a5=bp[5]; a6=bp[6]; a7=bp[7];
    }
#define A4(D,S) D.x+=S.x; D.y+=S.y; D.z+=S.z; D.w+=S.w;
    {
      const int self = nf[node];
      const float4* p = (const float4*)(embW1 + (size_t)self*DIM + part*32);
      float4 t0=p[0],t1=p[1],t2=p[2],t3=p[3],t4=p[4],t5=p[5],t6=p[6],t7=p[7];
      A4(a0,t0) A4(a1,t1) A4(a2,t2) A4(a3,t3) A4(a4,t4) A4(a5,t5) A4(a6,t6) A4(a7,t7)
    }
    int m = cnt[node]; if (m > CAP) m = CAP;
    const unsigned short* sl = slots + (size_t)node*CAP;
    const uint4 sv0 = *(const uint4*)(sl);
    const uint4 sv1 = *(const uint4*)(sl + 8);
    const uint4 sv2 = *(const uint4*)(sl + 16);
    const int mm = (m < 24) ? m : 24;
#define PAIR(W, E) \
    if ((E) < mm) { \
      const float4* p0 = (const float4*)(embW1 + (size_t)((W)&0xffffu)*DIM + part*32); \
      const bool two = ((E)+1 < mm); \
      const float4* p1 = two ? (const float4*)(embW1 + (size_t)((W)>>16)*DIM + part*32) : p0; \
      float4 t0=p0[0],t1=p0[1],t2=p0[2],t3=p0[3],t4=p0[4],t5=p0[5],t6=p0[6],t7=p0[7]; \
      float4 u0=p1[0],u1=p1[1],u2=p1[2],u3=p1[3],u4=p1[4],u5=p1[5],u6=p1[6],u7=p1[7]; \
      A4(a0,t0) A4(a1,t1) A4(a2,t2) A4(a3,t3) A4(a4,t4) A4(a5,t5) A4(a6,t6) A4(a7,t7) \
      if (two) { A4(a0,u0) A4(a1,u1) A4(a2,u2) A4(a3,u3) A4(a4,u4) A4(a5,u5) A4(a6,u6) A4(a7,u7) } \
    }
    PAIR(sv0.x, 0)  PAIR(sv0.y, 2)  PAIR(sv0.z, 4)  PAIR(sv0.w, 6)
    PAIR(sv1.x, 8)  PAIR(sv1.y,10)  PAIR(sv1.z,12)  PAIR(sv1.w,14)
    PAIR(sv2.x,16)  PAIR(sv2.y,18)  PAIR(sv2.z,20)  PAIR(sv2.w,22)
    for (int e = 24; e < m; ++e) {      // Poisson(8) tail: ~never
      const float4* p = (const float4*)(embW1 + (size_t)sl[e]*DIM + part*32);
      float4 t0=p[0],t1=p[1],t2=p[2],t3=p[3],t4=p[4],t5=p[5],t6=p[6],t7=p[7];
      A4(a0,t0) A4(a1,t1) A4(a2,t2) A4(a3,t3) A4(a4,t4) A4(a5,t5) A4(a6,t6) A4(a7,t7)
    }
    float s = 0.f, qs = 0.f;
#define SQ(V) s += V.x+V.y+V.z+V.w; qs += V.x*V.x+V.y*V.y+V.z*V.z+V.w*V.w;
    SQ(a0) SQ(a1) SQ(a2) SQ(a3) SQ(a4) SQ(a5) SQ(a6) SQ(a7)
    s  += __shfl_xor(s, 1, 64);  s  += __shfl_xor(s, 2, 64);
    qs += __shfl_xor(qs, 1, 64); qs += __shfl_xor(qs, 2, 64);
    const float mean = s * (1.f/128.f);
    const float var  = qs * (1.f/128.f) - mean*mean;
    const float rs   = rsqrtf(var + 1e-5f);
    float4 aa[8] = {a0,a1,a2,a3,a4,a5,a6,a7};
    #pragma unroll
    for (int q = 0; q < 8; ++q) {
      float4 gv = ((const float4*)g1 )[part*8 + q];
      float4 bv = ((const float4*)be1)[part*8 + q];
      float v0 = fmaxf((aa[q].x - mean)*rs*gv.x + bv.x, 0.f);
      float v1 = fmaxf((aa[q].y - mean)*rs*gv.y + bv.y, 0.f);
      float v2 = fmaxf((aa[q].z - mean)*rs*gv.z + bv.z, 0.f);
      float v3 = fmaxf((aa[q].w - mean)*rs*gv.w + bv.w, 0.f);
      uint2 pk;
      pk.x = (unsigned)f2bf(v0) | ((unsigned)f2bf(v1) << 16);
      pk.y = (unsigned)f2bf(v2) | ((unsigned)f2bf(v3) << 16);
      *(uint2*)&act[r][part*32 + q*4] = pk;
    }
  }
  __syncthreads();

  const int wave = tid >> 6, lane = tid & 63;
  const int l15 = lane & 15, lg = lane >> 4;
  const int arow = wave*16 + l15;
  const short8* ws8 = (const short8*)wswz;   // [s*2048 + ks*512 + n*64 + lane]

  for (int s = 0; s < 3; ++s) {
    f32x4 acc[8];
    #pragma unroll
    for (int n = 0; n < 8; ++n) acc[n] = (f32x4){0.f,0.f,0.f,0.f};
    #pragma unroll
    for (int ks = 0; ks < 4; ++ks) {
      short8 af = *(const short8*)&act[arow][ks*32 + lg*8];
      #pragma unroll
      for (int n = 0; n < 8; ++n) {
        short8 bf = ws8[s*2048 + ks*512 + n*64 + lane];
        acc[n] = __builtin_amdgcn_mfma_f32_16x16x32_bf16(af, bf, acc[n], 0, 0, 0);
      }
    }
    __syncthreads();   // all reads of act done before overwrite

    if (s < 2) {
      const float* bias = (s == 0) ? b2 : pb1;
      #pragma unroll
      for (int n = 0; n < 8; ++n) {
        const float bb = bias[n*16 + l15];
        #pragma unroll
        for (int r = 0; r < 4; ++r) {
          float v = acc[n][r] + bb;
          if (s == 1) v = fmaxf(v, 0.f);
          act[wave*16 + lg*4 + r][n*16 + l15] = f2bf(v);
        }
      }
      __syncthreads();
    } else {
      // final LayerNorm, write back to act, per-graph column partial sums
      float sr[4] = {0,0,0,0}, qr[4] = {0,0,0,0};
      #pragma unroll
      for (int n = 0; n < 8; ++n) {
        const float bb = pb2[n*16 + l15];
        #pragma unroll
        for (int r = 0; r < 4; ++r) {
          float v = acc[n][r] + bb; acc[n][r] = v;
          sr[r] += v; qr[r] += v*v;
        }
      }
      #pragma unroll
      for (int r = 0; r < 4; ++r) {
        #pragma unroll
        for (int msk = 1; msk < 16; msk <<= 1) {
          sr[r] += __shfl_xor(sr[r], msk, 64);
          qr[r] += __shfl_xor(qr[r], msk, 64);
        }
      }
      float mean[4], rs[4];
      #pragma unroll
      for (int r = 0; r < 4; ++r) {
        mean[r] = sr[r]*(1.f/128.f);
        float var = qr[r]*(1.f/128.f) - mean[r]*mean[r];
        rs[r] = rsqrtf(var + 1e-5f);
      }
      float pc[8];
      #pragma unroll
      for (int n = 0; n < 8; ++n) pc[n] = 0.f;
      #pragma unroll
      for (int n = 0; n < 8; ++n) {
        const int col = n*16 + l15;
        const float gc = ng[col], bc = nbv[col];
        #pragma unroll
        for (int r = 0; r < 4; ++r) {
          float xo = (acc[n][r] - mean[r])*rs[r]*gc + bc;
          act[wave*16 + lg*4 + r][col] = f2bf(xo);
          pc[n] += xo;
        }
      }
      #pragma unroll
      for (int n = 0; n < 8; ++n) {
        pc[n] += __shfl_xor(pc[n], 16, 64);
        pc[n] += __shfl_xor(pc[n], 32, 64);
      }
      if (lane < 16) {
        #pragma unroll
        for (int n = 0; n < 8; ++n) gpart[wave][n*16 + lane] = pc[n];
      }
      __syncthreads();
      if (tid < 128) {
        float s2 = gpart[0][tid] + gpart[1][tid] + gpart[2][tid] + gpart[3][tid];
        atomicAdd(&gsum[(blockIdx.x >> 3)*DIM + tid], s2);
      }
      // coalesced swizzled store: xswz element (rowgrp, kc, l15, j) = x[rowgrp*16+l15][kc*8+j]
      {
        short8* xs8 = (short8*)xswz;
        #pragma unroll
        for (int i = tid; i < 1024; i += 256) {
          int rowgrp = i >> 8, rem = i & 255;
          int kc = rem >> 4, lv = rem & 15;
          short8 v = *(const short8*)&act[rowgrp*16 + lv][kc*8];
          xs8[((size_t)(nbase >> 4) + rowgrp)*256 + kc*16 + lv] = v;
        }
      }
    }
  }
}

// ---------------- means -> exit MLP -> action_type ----------------
__global__ __launch_bounds__(128) void k_exit(const float* __restrict__ gsum,
    const float* __restrict__ W1, const float* __restrict__ b1,
    const float* __restrict__ g,  const float* __restrict__ be,
    const float* __restrict__ W2, const float* __restrict__ b2,
    float* __restrict__ out)
{
  const int gi = blockIdx.x, tid = threadIdx.x;
  __shared__ float mrow[DIM];
  __shared__ float red[4];
  __shared__ float red2[2];
  mrow[tid] = gsum[gi*DIM + tid] * (1.f/512.f);
  __syncthreads();
  float u = b1[tid];
  #pragma unroll 8
  for (int k = 0; k < DIM; ++k) u = fmaf(mrow[k], W1[k*DIM + tid], u);
  float s = u, q = u*u;
  #pragma unroll
  for (int m = 1; m < 64; m <<= 1) { s += __shfl_xor(s, m, 64); q += __shfl_xor(q, m, 64); }
  const int wv = tid >> 6;
  if ((tid & 63) == 0) { red[wv*2] = s; red[wv*2+1] = q; }
  __syncthreads();
  const float S = red[0] + red[2], Q = red[1] + red[3];
  const float mean = S*(1.f/128.f);
  const float var  = Q*(1.f/128.f) - mean*mean;
  float a = fmaxf((u - mean)*rsqrtf(var + 1e-5f)*g[tid] + be[tid], 0.f);
  float p = a * W2[tid];
  #pragma unroll
  for (int m = 1; m < 64; m <<= 1) p += __shfl_xor(p, m, 64);
  if ((tid & 63) == 0) red2[wv] = p;
  __syncthreads();
  if (tid == 0) {
    float e = red2[0] + red2[1] + b2[0];
    out[gi*3 + 1] = 1.f - e;
    out[gi*3 + 2] = e;
  }
}

// ---------------- batched X X^T from swizzled x, packed triu write ----------
__global__ __launch_bounds__(256) void k_scores(const unsigned short* __restrict__ xswz,
                                                float* __restrict__ out)
{
  static const int TI[10] = {0,0,0,0,1,1,1,2,2,3};
  static const int TJ[10] = {0,1,2,3,1,2,3,2,3,3};
  const int b = blockIdx.x / 10, p = blockIdx.x % 10;
  const int ti = TI[p], tj = TJ[p];
  const int tid = threadIdx.x;
  const int wave = tid >> 6, lane = tid & 63;
  const int l15 = lane & 15, lg = lane >> 4;
  const short8* Xs = (const short8*)xswz + (size_t)b*8192;  // 512*128/8

  f32x4 acc0[8], acc1[8];
  #pragma unroll
  for (int n = 0; n < 8; ++n) { acc0[n] = (f32x4){0,0,0,0}; acc1[n] = (f32x4){0,0,0,0}; }

  #pragma unroll
  for (int ks = 0; ks < 4; ++ks) {
    const int kq = ks*4 + lg;
    short8 a0 = Xs[(size_t)(ti*8 + wave*2 + 0)*256 + kq*16 + l15];
    short8 a1 = Xs[(size_t)(ti*8 + wave*2 + 1)*256 + kq*16 + l15];
    #pragma unroll
    for (int n = 0; n < 8; ++n) {
      short8 bf = Xs[(size_t)(tj*8 + n)*256 + kq*16 + l15];
      acc0[n] = __builtin_amdgcn_mfma_f32_16x16x32_bf16(a0, bf, acc0[n], 0, 0, 0);
      acc1[n] = __builtin_amdgcn_mfma_f32_16x16x32_bf16(a1, bf, acc1[n], 0, 0, 0);
    }
  }

  const float scale = 0.08838834764831845f;   // 1/sqrt(128)
  float* ea = out + 3072 + (size_t)b*EPB;
  #pragma unroll
  for (int m = 0; m < 2; ++m) {
    #pragma unroll
    for (int n = 0; n < 8; ++n) {
      const int gj = tj*128 + n*16 + l15;
      #pragma unroll
      for (int r = 0; r < 4; ++r) {
        const int gi = ti*128 + wave*32 + m*16 + lg*4 + r;
        if (gi < gj) {
          const int rowbase = gi*511 - (gi*(gi-1))/2 - gi - 1;
          const float v = (m == 0) ? acc0[n][r] : acc1[n][r];
          ea[rowbase + gj] = v * scale;
        }
      }
    }
  }
}

extern "C" void kernel_launch(void* const* d_in, const int* in_sizes, int n_in,
                              void* d_out, int out_size, void* d_ws, size_t ws_size,
                              hipStream_t stream) {
  const int*   nf   = (const int*)d_in[0];
  const int*   ei   = (const int*)d_in[1];
  const float* emb  = (const float*)d_in[3];
  const float* gW1  = (const float*)d_in[4];
  const float* gb1  = (const float*)d_in[5];
  const float* gg1  = (const float*)d_in[6];
  const float* gbe1 = (const float*)d_in[7];
  const float* gW2  = (const float*)d_in[8];
  const float* gb2  = (const float*)d_in[9];
  const float* pW1  = (const float*)d_in[10];
  const float* pb1  = (const float*)d_in[11];
  const float* pW2  = (const float*)d_in[12];
  const float* pb2  = (const float*)d_in[13];
  const float* ng   = (const float*)d_in[14];
  const float* nb   = (const float*)d_in[15];
  const float* eW1  = (const float*)d_in[16];
  const float* eb1  = (const float*)d_in[17];
  const float* eg   = (const float*)d_in[18];
  const float* ebe  = (const float*)d_in[19];
  const float* eW2  = (const float*)d_in[20];
  const float* eb2  = (const float*)d_in[21];
  float* out = (float*)d_out;

  char* ws = (char*)d_ws;
  float*          embW1 = (float*)ws;                          // 262144 B
  unsigned short* wswz  = (unsigned short*)(ws + 262144);      // 98304 B
  int*            cnt   = (int*)(ws + 360448);                 // 524288 B
  unsigned short* slots = (unsigned short*)(ws + 884736);      // 12582912 B
  unsigned short* xswz  = (unsigned short*)(ws + 13467648);    // 33554432 B
  float*          gsum  = (float*)(ws + 47022080);             // 131072 B
  if (ws_size < 47153152) return;

  hipMemsetAsync(cnt, 0, NTOT*sizeof(int), stream);
  hipMemsetAsync(gsum, 0, NBATCH*DIM*sizeof(float), stream);
  hipMemsetAsync(out, 0, 3072*sizeof(float), stream);

  k_embw1 <<<512, 128, 0, stream>>>(emb, gW1, embW1);
  k_cvtT  <<<192, 256, 0, stream>>>(gW2, pW1, pW2, wswz);
  k_edges <<<NEDGE/256, 256, 0, stream>>>(ei, nf, cnt, slots);
  k_gin   <<<2048, 256, 0, stream>>>(embW1, nf, cnt, slots, gb1, gg1, gbe1,
                                     wswz, gb2, pb1, pb2, ng, nb, xswz, gsum);
  k_exit  <<<256, 128, 0, stream>>>(gsum, eW1, eb1, eg, ebe, eW2, eb2, out);
  k_scores<<<2560, 256, 0, stream>>>(xswz, out);
}

// Round 3
// 229.499 us; speedup vs baseline: 1.5819x; 1.1840x over previous
//
#include <hip/hip_runtime.h>
#include <hip/hip_bf16.h>

#define NBATCH 256
#define NNODES 512
#define DIM    128
#define NTOT   (NBATCH*NNODES)   // 131072
#define NEDGE  (NTOT*8)          // 1048576
#define EPB    130816            // NNODES*(NNODES-1)/2
#define CAP    48

typedef __attribute__((ext_vector_type(8))) short  short8;
typedef __attribute__((ext_vector_type(4))) float  f32x4;

__device__ __forceinline__ unsigned short f2bf(float f){
  unsigned u = __builtin_bit_cast(unsigned, f);
  unsigned r = u + 0x7FFFu + ((u >> 16) & 1u);   // RNE
  return (unsigned short)(r >> 16);
}

// ---------------- prep: embW1 = emb @ gin_W1 (fp32, 512x128) ----------------
__global__ __launch_bounds__(128) void k_embw1(const float* __restrict__ emb,
                                               const float* __restrict__ W1,
                                               float* __restrict__ embW1){
  const int r = blockIdx.x, c = threadIdx.x;
  __shared__ float er[DIM];
  er[c] = emb[r*DIM + c];
  __syncthreads();
  float acc = 0.f;
  #pragma unroll 8
  for (int k = 0; k < DIM; ++k) acc = fmaf(er[k], W1[k*DIM + c], acc);
  embW1[r*DIM + c] = acc;
}

// ------- prep: 3 weights -> bf16 in MFMA B-frag order [s][ks][n][lane][j] ----
__global__ __launch_bounds__(256) void k_cvtT(const float* __restrict__ W2,
                                              const float* __restrict__ P1,
                                              const float* __restrict__ P2,
                                              unsigned short* __restrict__ dst){
  int idx = blockIdx.x*256 + threadIdx.x;          // 49152 total
  int s = idx >> 14, rem = idx & 16383;
  int ks = rem >> 12, n = (rem >> 9) & 7, lane = (rem >> 3) & 63, j = rem & 7;
  int lg = lane >> 4, l15 = lane & 15;
  int k = ks*32 + lg*8 + j, c = n*16 + l15;
  const float* src = (s == 0) ? W2 : ((s == 1) ? P1 : P2);
  dst[idx] = f2bf(src[k*DIM + c]);
}

// ---------------- edge scatter into capped per-node slots ----------------
__global__ __launch_bounds__(256) void k_edges(const int* __restrict__ ei,
                                               const int* __restrict__ nf,
                                               int* __restrict__ cnt,
                                               unsigned short* __restrict__ slots){
  int e = blockIdx.x*256 + threadIdx.x;
  int s = ei[e];
  int d = ei[NEDGE + e];
  int v = nf[s];
  int pos = atomicAdd(&cnt[d], 1);
  if (pos < CAP) slots[(size_t)d*CAP + pos] = (unsigned short)v;
}

// ------- gather + LN + relu -> bf16 row-major  (32 threads per node) -------
#define A4(D,S) D.x+=S.x; D.y+=S.y; D.z+=S.z; D.w+=S.w;
__global__ __launch_bounds__(512) void k_gather(
    const float* __restrict__ embW1, const int* __restrict__ nf,
    const int* __restrict__ cnt, const unsigned short* __restrict__ slots,
    const float* __restrict__ b1, const float* __restrict__ g1,
    const float* __restrict__ be1,
    unsigned short* __restrict__ xbuf)
{
  const int tid  = threadIdx.x;
  const int node = blockIdx.x*16 + (tid >> 5);
  const int part = tid & 31;                       // which float4 of the row
  const float4* base4 = (const float4*)embW1;

  const int self = nf[node];
  int m = cnt[node]; if (m > CAP) m = CAP;
  const unsigned short* sl = slots + (size_t)node*CAP;
  const uint4 sv0 = *(const uint4*)(sl);
  const uint4 sv1 = *(const uint4*)(sl + 8);
  const uint4 sv2 = *(const uint4*)(sl + 16);
  unsigned sw[12] = {sv0.x,sv0.y,sv0.z,sv0.w, sv1.x,sv1.y,sv1.z,sv1.w,
                     sv2.x,sv2.y,sv2.z,sv2.w};

  float4 acc = ((const float4*)b1)[part];

  // batch 1: self + neighbors 0..7  (9 independent loads in flight)
  {
    float4 t[9];
    t[0] = base4[(size_t)self*32 + part];
    #pragma unroll
    for (int e = 0; e < 8; ++e) {
      unsigned id = (sw[e >> 1] >> ((e & 1)*16)) & 0xffffu;
      int idx = (e < m) ? (int)id : self;
      t[e+1] = base4[(size_t)idx*32 + part];
    }
    A4(acc, t[0])
    #pragma unroll
    for (int e = 0; e < 8; ++e) if (e < m) { A4(acc, t[e+1]) }
  }
  if (m > 8) {
    float4 u[8];
    #pragma unroll
    for (int e = 0; e < 8; ++e) {
      unsigned id = (sw[4 + (e >> 1)] >> ((e & 1)*16)) & 0xffffu;
      int idx = (e + 8 < m) ? (int)id : self;
      u[e] = base4[(size_t)idx*32 + part];
    }
    #pragma unroll
    for (int e = 0; e < 8; ++e) if (e + 8 < m) { A4(acc, u[e]) }
  }
  if (m > 16) {
    float4 u[8];
    #pragma unroll
    for (int e = 0; e < 8; ++e) {
      unsigned id = (sw[8 + (e >> 1)] >> ((e & 1)*16)) & 0xffffu;
      int idx = (e + 16 < m) ? (int)id : self;
      u[e] = base4[(size_t)idx*32 + part];
    }
    #pragma unroll
    for (int e = 0; e < 8; ++e) if (e + 16 < m) { A4(acc, u[e]) }
  }
  for (int e = 24; e < m; ++e) {                   // Poisson(8): ~never
    float4 t = base4[(size_t)sl[e]*32 + part];
    A4(acc, t)
  }

  // LayerNorm over the 32-lane half-wave
  float s  = acc.x + acc.y + acc.z + acc.w;
  float qs = acc.x*acc.x + acc.y*acc.y + acc.z*acc.z + acc.w*acc.w;
  #pragma unroll
  for (int msk = 1; msk < 32; msk <<= 1) {
    s  += __shfl_xor(s,  msk, 64);
    qs += __shfl_xor(qs, msk, 64);
  }
  const float mean = s * (1.f/128.f);
  const float var  = qs * (1.f/128.f) - mean*mean;
  const float rs   = rsqrtf(var + 1e-5f);
  const float4 gv = ((const float4*)g1 )[part];
  const float4 bv = ((const float4*)be1)[part];
  float v0 = fmaxf((acc.x - mean)*rs*gv.x + bv.x, 0.f);
  float v1 = fmaxf((acc.y - mean)*rs*gv.y + bv.y, 0.f);
  float v2 = fmaxf((acc.z - mean)*rs*gv.z + bv.z, 0.f);
  float v3 = fmaxf((acc.w - mean)*rs*gv.w + bv.w, 0.f);
  uint2 pk;
  pk.x = (unsigned)f2bf(v0) | ((unsigned)f2bf(v1) << 16);
  pk.y = (unsigned)f2bf(v2) | ((unsigned)f2bf(v3) << 16);
  *(uint2*)(xbuf + (size_t)node*DIM + part*4) = pk;
}

// ---------------- 3x MFMA stages + final LN (in-place frag-swizzle) --------
// 2048 blocks x 256 thr; each block: 64 node rows.
__global__ __launch_bounds__(256, 4) void k_mlp(
    const unsigned short* __restrict__ wswz,   // [3][4ks][8n][64lane][8j]
    const float* __restrict__ b2,  const float* __restrict__ pb1, const float* __restrict__ pb2,
    const float* __restrict__ ng,  const float* __restrict__ nbv,
    unsigned short* __restrict__ xbuf, float* __restrict__ gsum)
{
  __shared__ unsigned short act[64][136];
  __shared__ float gpart[4][128];
  const int tid   = threadIdx.x;
  const int nbase = blockIdx.x * 64;

  // stage tile global -> LDS (coalesced)
  {
    const short8* src = (const short8*)(xbuf + (size_t)nbase*DIM);
    #pragma unroll
    for (int i = tid; i < 1024; i += 256) {
      int row = i >> 4, c8 = i & 15;
      *(short8*)&act[row][c8*8] = src[i];
    }
  }
  __syncthreads();

  const int wave = tid >> 6, lane = tid & 63;
  const int l15 = lane & 15, lg = lane >> 4;
  const int arow = wave*16 + l15;
  const short8* ws8 = (const short8*)wswz;

  for (int s = 0; s < 3; ++s) {
    f32x4 acc[8];
    #pragma unroll
    for (int n = 0; n < 8; ++n) acc[n] = (f32x4){0.f,0.f,0.f,0.f};
    #pragma unroll
    for (int ks = 0; ks < 4; ++ks) {
      short8 af = *(const short8*)&act[arow][ks*32 + lg*8];
      #pragma unroll
      for (int n = 0; n < 8; ++n) {
        short8 bf = ws8[s*2048 + ks*512 + n*64 + lane];
        acc[n] = __builtin_amdgcn_mfma_f32_16x16x32_bf16(af, bf, acc[n], 0, 0, 0);
      }
    }
    __syncthreads();

    if (s < 2) {
      const float* bias = (s == 0) ? b2 : pb1;
      #pragma unroll
      for (int n = 0; n < 8; ++n) {
        const float bb = bias[n*16 + l15];
        #pragma unroll
        for (int r = 0; r < 4; ++r) {
          float v = acc[n][r] + bb;
          if (s == 1) v = fmaxf(v, 0.f);
          act[wave*16 + lg*4 + r][n*16 + l15] = f2bf(v);
        }
      }
      __syncthreads();
    } else {
      float sr[4] = {0,0,0,0}, qr[4] = {0,0,0,0};
      #pragma unroll
      for (int n = 0; n < 8; ++n) {
        const float bb = pb2[n*16 + l15];
        #pragma unroll
        for (int r = 0; r < 4; ++r) {
          float v = acc[n][r] + bb; acc[n][r] = v;
          sr[r] += v; qr[r] += v*v;
        }
      }
      #pragma unroll
      for (int r = 0; r < 4; ++r) {
        #pragma unroll
        for (int msk = 1; msk < 16; msk <<= 1) {
          sr[r] += __shfl_xor(sr[r], msk, 64);
          qr[r] += __shfl_xor(qr[r], msk, 64);
        }
      }
      float mean[4], rs[4];
      #pragma unroll
      for (int r = 0; r < 4; ++r) {
        mean[r] = sr[r]*(1.f/128.f);
        float var = qr[r]*(1.f/128.f) - mean[r]*mean[r];
        rs[r] = rsqrtf(var + 1e-5f);
      }
      float pc[8];
      #pragma unroll
      for (int n = 0; n < 8; ++n) pc[n] = 0.f;
      #pragma unroll
      for (int n = 0; n < 8; ++n) {
        const int col = n*16 + l15;
        const float gc = ng[col], bc = nbv[col];
        #pragma unroll
        for (int r = 0; r < 4; ++r) {
          float xo = (acc[n][r] - mean[r])*rs[r]*gc + bc;
          act[wave*16 + lg*4 + r][col] = f2bf(xo);
          pc[n] += xo;
        }
      }
      #pragma unroll
      for (int n = 0; n < 8; ++n) {
        pc[n] += __shfl_xor(pc[n], 16, 64);
        pc[n] += __shfl_xor(pc[n], 32, 64);
      }
      if (lane < 16) {
        #pragma unroll
        for (int n = 0; n < 8; ++n) gpart[wave][n*16 + lane] = pc[n];
      }
      __syncthreads();
      if (tid < 128) {
        float s2 = gpart[0][tid] + gpart[1][tid] + gpart[2][tid] + gpart[3][tid];
        atomicAdd(&gsum[(blockIdx.x >> 3)*DIM + tid], s2);
      }
      // frag-swizzled store (in place over this block's own row range)
      {
        short8* xs8 = (short8*)xbuf;
        #pragma unroll
        for (int i = tid; i < 1024; i += 256) {
          int rowgrp = i >> 8, rem = i & 255;
          int kc = rem >> 4, lv = rem & 15;
          short8 v = *(const short8*)&act[rowgrp*16 + lv][kc*8];
          xs8[((size_t)(nbase >> 4) + rowgrp)*256 + kc*16 + lv] = v;
        }
      }
    }
  }
}

// ---------------- means -> exit MLP -> action_type ----------------
__global__ __launch_bounds__(128) void k_exit(const float* __restrict__ gsum,
    const float* __restrict__ W1, const float* __restrict__ b1,
    const float* __restrict__ g,  const float* __restrict__ be,
    const float* __restrict__ W2, const float* __restrict__ b2,
    float* __restrict__ out)
{
  const int gi = blockIdx.x, tid = threadIdx.x;
  __shared__ float mrow[DIM];
  __shared__ float red[4];
  __shared__ float red2[2];
  mrow[tid] = gsum[gi*DIM + tid] * (1.f/512.f);
  __syncthreads();
  float u = b1[tid];
  #pragma unroll 8
  for (int k = 0; k < DIM; ++k) u = fmaf(mrow[k], W1[k*DIM + tid], u);
  float s = u, q = u*u;
  #pragma unroll
  for (int m = 1; m < 64; m <<= 1) { s += __shfl_xor(s, m, 64); q += __shfl_xor(q, m, 64); }
  const int wv = tid >> 6;
  if ((tid & 63) == 0) { red[wv*2] = s; red[wv*2+1] = q; }
  __syncthreads();
  const float S = red[0] + red[2], Q = red[1] + red[3];
  const float mean = S*(1.f/128.f);
  const float var  = Q*(1.f/128.f) - mean*mean;
  float a = fmaxf((u - mean)*rsqrtf(var + 1e-5f)*g[tid] + be[tid], 0.f);
  float p = a * W2[tid];
  #pragma unroll
  for (int m = 1; m < 64; m <<= 1) p += __shfl_xor(p, m, 64);
  if ((tid & 63) == 0) red2[wv] = p;
  __syncthreads();
  if (tid == 0) {
    float e = red2[0] + red2[1] + b2[0];
    out[gi*3 + 1] = 1.f - e;
    out[gi*3 + 2] = e;
  }
}

// ---------------- batched X X^T from swizzled x, packed triu write ----------
__global__ __launch_bounds__(256) void k_scores(const unsigned short* __restrict__ xswz,
                                                float* __restrict__ out)
{
  static const int TI[10] = {0,0,0,0,1,1,1,2,2,3};
  static const int TJ[10] = {0,1,2,3,1,2,3,2,3,3};
  const int b = blockIdx.x / 10, p = blockIdx.x % 10;
  const int ti = TI[p], tj = TJ[p];
  const int tid = threadIdx.x;
  const int wave = tid >> 6, lane = tid & 63;
  const int l15 = lane & 15, lg = lane >> 4;
  const short8* Xs = (const short8*)xswz + (size_t)b*8192;  // 512*128/8

  f32x4 acc0[8], acc1[8];
  #pragma unroll
  for (int n = 0; n < 8; ++n) { acc0[n] = (f32x4){0,0,0,0}; acc1[n] = (f32x4){0,0,0,0}; }

  #pragma unroll
  for (int ks = 0; ks < 4; ++ks) {
    const int kq = ks*4 + lg;
    short8 a0 = Xs[(size_t)(ti*8 + wave*2 + 0)*256 + kq*16 + l15];
    short8 a1 = Xs[(size_t)(ti*8 + wave*2 + 1)*256 + kq*16 + l15];
    #pragma unroll
    for (int n = 0; n < 8; ++n) {
      short8 bf = Xs[(size_t)(tj*8 + n)*256 + kq*16 + l15];
      acc0[n] = __builtin_amdgcn_mfma_f32_16x16x32_bf16(a0, bf, acc0[n], 0, 0, 0);
      acc1[n] = __builtin_amdgcn_mfma_f32_16x16x32_bf16(a1, bf, acc1[n], 0, 0, 0);
    }
  }

  const float scale = 0.08838834764831845f;   // 1/sqrt(128)
  float* ea = out + 3072 + (size_t)b*EPB;
  #pragma unroll
  for (int m = 0; m < 2; ++m) {
    #pragma unroll
    for (int n = 0; n < 8; ++n) {
      const int gj = tj*128 + n*16 + l15;
      #pragma unroll
      for (int r = 0; r < 4; ++r) {
        const int gi = ti*128 + wave*32 + m*16 + lg*4 + r;
        if (gi < gj) {
          const int rowbase = gi*511 - (gi*(gi-1))/2 - gi - 1;
          const float v = (m == 0) ? acc0[n][r] : acc1[n][r];
          ea[rowbase + gj] = v * scale;
        }
      }
    }
  }
}

extern "C" void kernel_launch(void* const* d_in, const int* in_sizes, int n_in,
                              void* d_out, int out_size, void* d_ws, size_t ws_size,
                              hipStream_t stream) {
  const int*   nf   = (const int*)d_in[0];
  const int*   ei   = (const int*)d_in[1];
  const float* emb  = (const float*)d_in[3];
  const float* gW1  = (const float*)d_in[4];
  const float* gb1  = (const float*)d_in[5];
  const float* gg1  = (const float*)d_in[6];
  const float* gbe1 = (const float*)d_in[7];
  const float* gW2  = (const float*)d_in[8];
  const float* gb2  = (const float*)d_in[9];
  const float* pW1  = (const float*)d_in[10];
  const float* pb1  = (const float*)d_in[11];
  const float* pW2  = (const float*)d_in[12];
  const float* pb2  = (const float*)d_in[13];
  const float* ng   = (const float*)d_in[14];
  const float* nb   = (const float*)d_in[15];
  const float* eW1  = (const float*)d_in[16];
  const float* eb1  = (const float*)d_in[17];
  const float* eg   = (const float*)d_in[18];
  const float* ebe  = (const float*)d_in[19];
  const float* eW2  = (const float*)d_in[20];
  const float* eb2  = (const float*)d_in[21];
  float* out = (float*)d_out;

  char* ws = (char*)d_ws;
  float*          embW1 = (float*)ws;                          // 262144 B
  unsigned short* wswz  = (unsigned short*)(ws + 262144);      // 98304 B
  int*            cnt   = (int*)(ws + 360448);                 // 524288 B
  unsigned short* slots = (unsigned short*)(ws + 884736);      // 12582912 B
  unsigned short* xbuf  = (unsigned short*)(ws + 13467648);    // 33554432 B (act, then frag-swizzled x, in place)
  float*          gsum  = (float*)(ws + 47022080);             // 131072 B
  if (ws_size < 47153152) return;

  hipMemsetAsync(cnt, 0, NTOT*sizeof(int), stream);
  hipMemsetAsync(gsum, 0, NBATCH*DIM*sizeof(float), stream);
  hipMemsetAsync(out, 0, 3072*sizeof(float), stream);

  k_embw1 <<<512, 128, 0, stream>>>(emb, gW1, embW1);
  k_cvtT  <<<192, 256, 0, stream>>>(gW2, pW1, pW2, wswz);
  k_edges <<<NEDGE/256, 256, 0, stream>>>(ei, nf, cnt, slots);
  k_gather<<<8192, 512, 0, stream>>>(embW1, nf, cnt, slots, gb1, gg1, gbe1, xbuf);
  k_mlp   <<<2048, 256, 0, stream>>>(wswz, gb2, pb1, pb2, ng, nb, xbuf, gsum);
  k_exit  <<<256, 128, 0, stream>>>(gsum, eW1, eb1, eg, ebe, eW2, eb2, out);
  k_scores<<<2560, 256, 0, stream>>>(xbuf, out);
}

// Round 4
// 219.807 us; speedup vs baseline: 1.6517x; 1.0441x over previous
//
#include <hip/hip_runtime.h>
#include <hip/hip_bf16.h>

#define NBATCH 256
#define NNODES 512
#define DIM    128
#define NTOT   (NBATCH*NNODES)   // 131072
#define NEDGE  (NTOT*8)          // 1048576
#define EPB    130816            // NNODES*(NNODES-1)/2
#define CAP    48

typedef __attribute__((ext_vector_type(8))) short  short8;
typedef __attribute__((ext_vector_type(4))) float  f32x4;

__device__ __forceinline__ unsigned short f2bf(float f){
  unsigned u = __builtin_bit_cast(unsigned, f);
  unsigned r = u + 0x7FFFu + ((u >> 16) & 1u);   // RNE
  return (unsigned short)(r >> 16);
}

// ---- fused prep: embW1 GEMM + weight frag-swizzle + zero cnt/gsum/out ----
// blocks 0..255   : embW1 = emb @ gin_W1   (2 rows per block)
// blocks 256..447 : wswz  = bf16 frag-order [3][4ks][8n][64lane][8j]
// blocks 448..1099: zero cnt(131072 w) + gsum(32768 w) + out[0:3072]
__global__ __launch_bounds__(256) void k_prep(
    const float* __restrict__ emb, const float* __restrict__ W1,
    float* __restrict__ embW1,
    const float* __restrict__ W2, const float* __restrict__ P1,
    const float* __restrict__ P2, unsigned short* __restrict__ wswz,
    int* __restrict__ cnt, float* __restrict__ gsum, float* __restrict__ out)
{
  const int tid = threadIdx.x;
  const int blk = blockIdx.x;
  __shared__ float er[2][DIM];
  if (blk < 256) {
    const int half = tid >> 7, c = tid & 127;
    const int r = blk*2 + half;
    er[half][c] = emb[r*DIM + c];
    __syncthreads();
    float acc = 0.f;
    #pragma unroll 8
    for (int k = 0; k < DIM; ++k) acc = fmaf(er[half][k], W1[k*DIM + c], acc);
    embW1[r*DIM + c] = acc;
  } else if (blk < 448) {
    int idx = (blk - 256)*256 + tid;               // 49152 total
    int s = idx >> 14, rem = idx & 16383;
    int ks = rem >> 12, n = (rem >> 9) & 7, lane = (rem >> 3) & 63, j = rem & 7;
    int lg = lane >> 4, l15 = lane & 15;
    int k = ks*32 + lg*8 + j, c = n*16 + l15;
    const float* src = (s == 0) ? W2 : ((s == 1) ? P1 : P2);
    wswz[idx] = f2bf(src[k*DIM + c]);
  } else {
    int idx = (blk - 448)*256 + tid;               // 166912 total, exact
    if (idx < NTOT)                cnt[idx] = 0;
    else if (idx < NTOT + 32768)   gsum[idx - NTOT] = 0.f;
    else                           out[idx - NTOT - 32768] = 0.f;
  }
}

// ---------------- edge scatter into capped per-node slots ----------------
__global__ __launch_bounds__(256) void k_edges(const int* __restrict__ ei,
                                               const int* __restrict__ nf,
                                               int* __restrict__ cnt,
                                               unsigned short* __restrict__ slots){
  int e = blockIdx.x*256 + threadIdx.x;
  int s = ei[e];
  int d = ei[NEDGE + e];
  int v = nf[s];
  int pos = atomicAdd(&cnt[d], 1);
  if (pos < CAP) slots[(size_t)d*CAP + pos] = (unsigned short)v;
}

// ------- gather + LN + relu -> bf16 row-major  (32 threads per node) -------
#define A4(D,S) D.x+=S.x; D.y+=S.y; D.z+=S.z; D.w+=S.w;
__global__ __launch_bounds__(512) void k_gather(
    const float* __restrict__ embW1, const int* __restrict__ nf,
    const int* __restrict__ cnt, const unsigned short* __restrict__ slots,
    const float* __restrict__ b1, const float* __restrict__ g1,
    const float* __restrict__ be1,
    unsigned short* __restrict__ xbuf)
{
  const int tid  = threadIdx.x;
  const int node = blockIdx.x*16 + (tid >> 5);
  const int part = tid & 31;                       // which float4 of the row
  const float4* base4 = (const float4*)embW1;

  const int self = nf[node];
  int m = cnt[node]; if (m > CAP) m = CAP;
  const unsigned short* sl = slots + (size_t)node*CAP;
  const uint4 sv0 = *(const uint4*)(sl);
  const uint4 sv1 = *(const uint4*)(sl + 8);
  const uint4 sv2 = *(const uint4*)(sl + 16);
  unsigned sw[12] = {sv0.x,sv0.y,sv0.z,sv0.w, sv1.x,sv1.y,sv1.z,sv1.w,
                     sv2.x,sv2.y,sv2.z,sv2.w};

  float4 acc = ((const float4*)b1)[part];

  // batch 1: self + neighbors 0..7  (9 independent loads in flight)
  {
    float4 t[9];
    t[0] = base4[(size_t)self*32 + part];
    #pragma unroll
    for (int e = 0; e < 8; ++e) {
      unsigned id = (sw[e >> 1] >> ((e & 1)*16)) & 0xffffu;
      int idx = (e < m) ? (int)id : self;
      t[e+1] = base4[(size_t)idx*32 + part];
    }
    A4(acc, t[0])
    #pragma unroll
    for (int e = 0; e < 8; ++e) if (e < m) { A4(acc, t[e+1]) }
  }
  if (m > 8) {
    float4 u[8];
    #pragma unroll
    for (int e = 0; e < 8; ++e) {
      unsigned id = (sw[4 + (e >> 1)] >> ((e & 1)*16)) & 0xffffu;
      int idx = (e + 8 < m) ? (int)id : self;
      u[e] = base4[(size_t)idx*32 + part];
    }
    #pragma unroll
    for (int e = 0; e < 8; ++e) if (e + 8 < m) { A4(acc, u[e]) }
  }
  if (m > 16) {
    float4 u[8];
    #pragma unroll
    for (int e = 0; e < 8; ++e) {
      unsigned id = (sw[8 + (e >> 1)] >> ((e & 1)*16)) & 0xffffu;
      int idx = (e + 16 < m) ? (int)id : self;
      u[e] = base4[(size_t)idx*32 + part];
    }
    #pragma unroll
    for (int e = 0; e < 8; ++e) if (e + 16 < m) { A4(acc, u[e]) }
  }
  for (int e = 24; e < m; ++e) {                   // Poisson(8): ~never
    float4 t = base4[(size_t)sl[e]*32 + part];
    A4(acc, t)
  }

  // LayerNorm over the 32-lane half-wave
  float s  = acc.x + acc.y + acc.z + acc.w;
  float qs = acc.x*acc.x + acc.y*acc.y + acc.z*acc.z + acc.w*acc.w;
  #pragma unroll
  for (int msk = 1; msk < 32; msk <<= 1) {
    s  += __shfl_xor(s,  msk, 64);
    qs += __shfl_xor(qs, msk, 64);
  }
  const float mean = s * (1.f/128.f);
  const float var  = qs * (1.f/128.f) - mean*mean;
  const float rs   = rsqrtf(var + 1e-5f);
  const float4 gv = ((const float4*)g1 )[part];
  const float4 bv = ((const float4*)be1)[part];
  float v0 = fmaxf((acc.x - mean)*rs*gv.x + bv.x, 0.f);
  float v1 = fmaxf((acc.y - mean)*rs*gv.y + bv.y, 0.f);
  float v2 = fmaxf((acc.z - mean)*rs*gv.z + bv.z, 0.f);
  float v3 = fmaxf((acc.w - mean)*rs*gv.w + bv.w, 0.f);
  uint2 pk;
  pk.x = (unsigned)f2bf(v0) | ((unsigned)f2bf(v1) << 16);
  pk.y = (unsigned)f2bf(v2) | ((unsigned)f2bf(v3) << 16);
  *(uint2*)(xbuf + (size_t)node*DIM + part*4) = pk;
}

// ---------------- 3x MFMA stages + final LN (in-place frag-swizzle) --------
// 2048 blocks x 256 thr; each block: 64 node rows.
__global__ __launch_bounds__(256, 4) void k_mlp(
    const unsigned short* __restrict__ wswz,   // [3][4ks][8n][64lane][8j]
    const float* __restrict__ b2,  const float* __restrict__ pb1, const float* __restrict__ pb2,
    const float* __restrict__ ng,  const float* __restrict__ nbv,
    unsigned short* __restrict__ xbuf, float* __restrict__ gsum)
{
  __shared__ unsigned short act[64][136];
  __shared__ float gpart[4][128];
  const int tid   = threadIdx.x;
  const int nbase = blockIdx.x * 64;

  // stage tile global -> LDS (coalesced)
  {
    const short8* src = (const short8*)(xbuf + (size_t)nbase*DIM);
    #pragma unroll
    for (int i = tid; i < 1024; i += 256) {
      int row = i >> 4, c8 = i & 15;
      *(short8*)&act[row][c8*8] = src[i];
    }
  }
  __syncthreads();

  const int wave = tid >> 6, lane = tid & 63;
  const int l15 = lane & 15, lg = lane >> 4;
  const int arow = wave*16 + l15;
  const short8* ws8 = (const short8*)wswz;

  for (int s = 0; s < 3; ++s) {
    f32x4 acc[8];
    #pragma unroll
    for (int n = 0; n < 8; ++n) acc[n] = (f32x4){0.f,0.f,0.f,0.f};
    #pragma unroll
    for (int ks = 0; ks < 4; ++ks) {
      short8 af = *(const short8*)&act[arow][ks*32 + lg*8];
      #pragma unroll
      for (int n = 0; n < 8; ++n) {
        short8 bf = ws8[s*2048 + ks*512 + n*64 + lane];
        acc[n] = __builtin_amdgcn_mfma_f32_16x16x32_bf16(af, bf, acc[n], 0, 0, 0);
      }
    }
    __syncthreads();

    if (s < 2) {
      const float* bias = (s == 0) ? b2 : pb1;
      #pragma unroll
      for (int n = 0; n < 8; ++n) {
        const float bb = bias[n*16 + l15];
        #pragma unroll
        for (int r = 0; r < 4; ++r) {
          float v = acc[n][r] + bb;
          if (s == 1) v = fmaxf(v, 0.f);
          act[wave*16 + lg*4 + r][n*16 + l15] = f2bf(v);
        }
      }
      __syncthreads();
    } else {
      float sr[4] = {0,0,0,0}, qr[4] = {0,0,0,0};
      #pragma unroll
      for (int n = 0; n < 8; ++n) {
        const float bb = pb2[n*16 + l15];
        #pragma unroll
        for (int r = 0; r < 4; ++r) {
          float v = acc[n][r] + bb; acc[n][r] = v;
          sr[r] += v; qr[r] += v*v;
        }
      }
      #pragma unroll
      for (int r = 0; r < 4; ++r) {
        #pragma unroll
        for (int msk = 1; msk < 16; msk <<= 1) {
          sr[r] += __shfl_xor(sr[r], msk, 64);
          qr[r] += __shfl_xor(qr[r], msk, 64);
        }
      }
      float mean[4], rs[4];
      #pragma unroll
      for (int r = 0; r < 4; ++r) {
        mean[r] = sr[r]*(1.f/128.f);
        float var = qr[r]*(1.f/128.f) - mean[r]*mean[r];
        rs[r] = rsqrtf(var + 1e-5f);
      }
      float pc[8];
      #pragma unroll
      for (int n = 0; n < 8; ++n) pc[n] = 0.f;
      #pragma unroll
      for (int n = 0; n < 8; ++n) {
        const int col = n*16 + l15;
        const float gc = ng[col], bc = nbv[col];
        #pragma unroll
        for (int r = 0; r < 4; ++r) {
          float xo = (acc[n][r] - mean[r])*rs[r]*gc + bc;
          act[wave*16 + lg*4 + r][col] = f2bf(xo);
          pc[n] += xo;
        }
      }
      #pragma unroll
      for (int n = 0; n < 8; ++n) {
        pc[n] += __shfl_xor(pc[n], 16, 64);
        pc[n] += __shfl_xor(pc[n], 32, 64);
      }
      if (lane < 16) {
        #pragma unroll
        for (int n = 0; n < 8; ++n) gpart[wave][n*16 + lane] = pc[n];
      }
      __syncthreads();
      if (tid < 128) {
        float s2 = gpart[0][tid] + gpart[1][tid] + gpart[2][tid] + gpart[3][tid];
        atomicAdd(&gsum[(blockIdx.x >> 3)*DIM + tid], s2);
      }
      // frag-swizzled store (in place over this block's own row range)
      {
        short8* xs8 = (short8*)xbuf;
        #pragma unroll
        for (int i = tid; i < 1024; i += 256) {
          int rowgrp = i >> 8, rem = i & 255;
          int kc = rem >> 4, lv = rem & 15;
          short8 v = *(const short8*)&act[rowgrp*16 + lv][kc*8];
          xs8[((size_t)(nbase >> 4) + rowgrp)*256 + kc*16 + lv] = v;
        }
      }
    }
  }
}

// ---------------- means -> exit MLP -> action_type ----------------
__global__ __launch_bounds__(128) void k_exit(const float* __restrict__ gsum,
    const float* __restrict__ W1, const float* __restrict__ b1,
    const float* __restrict__ g,  const float* __restrict__ be,
    const float* __restrict__ W2, const float* __restrict__ b2,
    float* __restrict__ out)
{
  const int gi = blockIdx.x, tid = threadIdx.x;
  __shared__ float mrow[DIM];
  __shared__ float red[4];
  __shared__ float red2[2];
  mrow[tid] = gsum[gi*DIM + tid] * (1.f/512.f);
  __syncthreads();
  float u = b1[tid];
  #pragma unroll 8
  for (int k = 0; k < DIM; ++k) u = fmaf(mrow[k], W1[k*DIM + tid], u);
  float s = u, q = u*u;
  #pragma unroll
  for (int m = 1; m < 64; m <<= 1) { s += __shfl_xor(s, m, 64); q += __shfl_xor(q, m, 64); }
  const int wv = tid >> 6;
  if ((tid & 63) == 0) { red[wv*2] = s; red[wv*2+1] = q; }
  __syncthreads();
  const float S = red[0] + red[2], Q = red[1] + red[3];
  const float mean = S*(1.f/128.f);
  const float var  = Q*(1.f/128.f) - mean*mean;
  float a = fmaxf((u - mean)*rsqrtf(var + 1e-5f)*g[tid] + be[tid], 0.f);
  float p = a * W2[tid];
  #pragma unroll
  for (int m = 1; m < 64; m <<= 1) p += __shfl_xor(p, m, 64);
  if ((tid & 63) == 0) red2[wv] = p;
  __syncthreads();
  if (tid == 0) {
    float e = red2[0] + red2[1] + b2[0];
    out[gi*3 + 1] = 1.f - e;
    out[gi*3 + 2] = e;
  }
}

// ---------------- batched X X^T from swizzled x, packed triu write ----------
__global__ __launch_bounds__(256) void k_scores(const unsigned short* __restrict__ xswz,
                                                float* __restrict__ out)
{
  static const int TI[10] = {0,0,0,0,1,1,1,2,2,3};
  static const int TJ[10] = {0,1,2,3,1,2,3,2,3,3};
  const int b = blockIdx.x / 10, p = blockIdx.x % 10;
  const int ti = TI[p], tj = TJ[p];
  const int tid = threadIdx.x;
  const int wave = tid >> 6, lane = tid & 63;
  const int l15 = lane & 15, lg = lane >> 4;
  const short8* Xs = (const short8*)xswz + (size_t)b*8192;  // 512*128/8

  f32x4 acc0[8], acc1[8];
  #pragma unroll
  for (int n = 0; n < 8; ++n) { acc0[n] = (f32x4){0,0,0,0}; acc1[n] = (f32x4){0,0,0,0}; }

  #pragma unroll
  for (int ks = 0; ks < 4; ++ks) {
    const int kq = ks*4 + lg;
    short8 a0 = Xs[(size_t)(ti*8 + wave*2 + 0)*256 + kq*16 + l15];
    short8 a1 = Xs[(size_t)(ti*8 + wave*2 + 1)*256 + kq*16 + l15];
    #pragma unroll
    for (int n = 0; n < 8; ++n) {
      short8 bf = Xs[(size_t)(tj*8 + n)*256 + kq*16 + l15];
      acc0[n] = __builtin_amdgcn_mfma_f32_16x16x32_bf16(a0, bf, acc0[n], 0, 0, 0);
      acc1[n] = __builtin_amdgcn_mfma_f32_16x16x32_bf16(a1, bf, acc1[n], 0, 0, 0);
    }
  }

  const float scale = 0.08838834764831845f;   // 1/sqrt(128)
  float* ea = out + 3072 + (size_t)b*EPB;
  #pragma unroll
  for (int m = 0; m < 2; ++m) {
    #pragma unroll
    for (int n = 0; n < 8; ++n) {
      const int gj = tj*128 + n*16 + l15;
      #pragma unroll
      for (int r = 0; r < 4; ++r) {
        const int gi = ti*128 + wave*32 + m*16 + lg*4 + r;
        if (gi < gj) {
          const int rowbase = gi*511 - (gi*(gi-1))/2 - gi - 1;
          const float v = (m == 0) ? acc0[n][r] : acc1[n][r];
          ea[rowbase + gj] = v * scale;
        }
      }
    }
  }
}

extern "C" void kernel_launch(void* const* d_in, const int* in_sizes, int n_in,
                              void* d_out, int out_size, void* d_ws, size_t ws_size,
                              hipStream_t stream) {
  const int*   nf   = (const int*)d_in[0];
  const int*   ei   = (const int*)d_in[1];
  const float* emb  = (const float*)d_in[3];
  const float* gW1  = (const float*)d_in[4];
  const float* gb1  = (const float*)d_in[5];
  const float* gg1  = (const float*)d_in[6];
  const float* gbe1 = (const float*)d_in[7];
  const float* gW2  = (const float*)d_in[8];
  const float* gb2  = (const float*)d_in[9];
  const float* pW1  = (const float*)d_in[10];
  const float* pb1  = (const float*)d_in[11];
  const float* pW2  = (const float*)d_in[12];
  const float* pb2  = (const float*)d_in[13];
  const float* ng   = (const float*)d_in[14];
  const float* nb   = (const float*)d_in[15];
  const float* eW1  = (const float*)d_in[16];
  const float* eb1  = (const float*)d_in[17];
  const float* eg   = (const float*)d_in[18];
  const float* ebe  = (const float*)d_in[19];
  const float* eW2  = (const float*)d_in[20];
  const float* eb2  = (const float*)d_in[21];
  float* out = (float*)d_out;

  char* ws = (char*)d_ws;
  float*          embW1 = (float*)ws;                          // 262144 B
  unsigned short* wswz  = (unsigned short*)(ws + 262144);      // 98304 B
  int*            cnt   = (int*)(ws + 360448);                 // 524288 B
  unsigned short* slots = (unsigned short*)(ws + 884736);      // 12582912 B
  unsigned short* xbuf  = (unsigned short*)(ws + 13467648);    // 33554432 B
  float*          gsum  = (float*)(ws + 47022080);             // 131072 B
  if (ws_size < 47153152) return;

  k_prep  <<<1100, 256, 0, stream>>>(emb, gW1, embW1, gW2, pW1, pW2, wswz,
                                     cnt, gsum, out);
  k_edges <<<NEDGE/256, 256, 0, stream>>>(ei, nf, cnt, slots);
  k_gather<<<8192, 512, 0, stream>>>(embW1, nf, cnt, slots, gb1, gg1, gbe1, xbuf);
  k_mlp   <<<2048, 256, 0, stream>>>(wswz, gb2, pb1, pb2, ng, nb, xbuf, gsum);
  k_exit  <<<256, 128, 0, stream>>>(gsum, eW1, eb1, eg, ebe, eW2, eb2, out);
  k_scores<<<2560, 256, 0, stream>>>(xbuf, out);
}

// Round 5
// 198.190 us; speedup vs baseline: 1.8318x; 1.1091x over previous
//
#include <hip/hip_runtime.h>
#include <hip/hip_bf16.h>

#define NBATCH 256
#define NNODES 512
#define DIM    128
#define NTOT   (NBATCH*NNODES)   // 131072
#define NEDGE  (NTOT*8)          // 1048576
#define EPB    130816            // NNODES*(NNODES-1)/2
#define CAP    48

typedef __attribute__((ext_vector_type(8))) short  short8;
typedef __attribute__((ext_vector_type(4))) float  f32x4;

__device__ __forceinline__ unsigned short f2bf(float f){
  unsigned u = __builtin_bit_cast(unsigned, f);
  unsigned r = u + 0x7FFFu + ((u >> 16) & 1u);   // RNE
  return (unsigned short)(r >> 16);
}

// ---- fused prep: embW1 GEMM (bf16 out) + weight frag-swizzle + zeroing ----
// blocks 0..255   : embW1 = bf16(emb @ gin_W1)   (2 rows per block)
// blocks 256..447 : wswz  = bf16 frag-order [3][4ks][8n][64lane][8j]
// blocks 448..1099: zero cnt(131072 w) + gsum(32768 w) + out[0:3072]
__global__ __launch_bounds__(256) void k_prep(
    const float* __restrict__ emb, const float* __restrict__ W1,
    unsigned short* __restrict__ embW1,
    const float* __restrict__ W2, const float* __restrict__ P1,
    const float* __restrict__ P2, unsigned short* __restrict__ wswz,
    int* __restrict__ cnt, float* __restrict__ gsum, float* __restrict__ out)
{
  const int tid = threadIdx.x;
  const int blk = blockIdx.x;
  __shared__ float er[2][DIM];
  if (blk < 256) {
    const int half = tid >> 7, c = tid & 127;
    const int r = blk*2 + half;
    er[half][c] = emb[r*DIM + c];
    __syncthreads();
    float acc = 0.f;
    #pragma unroll 8
    for (int k = 0; k < DIM; ++k) acc = fmaf(er[half][k], W1[k*DIM + c], acc);
    embW1[r*DIM + c] = f2bf(acc);
  } else if (blk < 448) {
    int idx = (blk - 256)*256 + tid;               // 49152 total
    int s = idx >> 14, rem = idx & 16383;
    int ks = rem >> 12, n = (rem >> 9) & 7, lane = (rem >> 3) & 63, j = rem & 7;
    int lg = lane >> 4, l15 = lane & 15;
    int k = ks*32 + lg*8 + j, c = n*16 + l15;
    const float* src = (s == 0) ? W2 : ((s == 1) ? P1 : P2);
    wswz[idx] = f2bf(src[k*DIM + c]);
  } else {
    int idx = (blk - 448)*256 + tid;               // 166912 total, exact
    if (idx < NTOT)                cnt[idx] = 0;
    else if (idx < NTOT + 32768)   gsum[idx - NTOT] = 0.f;
    else                           out[idx - NTOT - 32768] = 0.f;
  }
}

// ---------------- edge scatter, 2 edges per thread ----------------
__global__ __launch_bounds__(256) void k_edges(const int* __restrict__ ei,
                                               const int* __restrict__ nf,
                                               int* __restrict__ cnt,
                                               unsigned short* __restrict__ slots){
  int e0 = blockIdx.x*512 + threadIdx.x;
  int e1 = e0 + 256;
  int s0 = ei[e0],        s1 = ei[e1];
  int d0 = ei[NEDGE + e0], d1 = ei[NEDGE + e1];
  int v0 = nf[s0],        v1 = nf[s1];
  int p0 = atomicAdd(&cnt[d0], 1);
  int p1 = atomicAdd(&cnt[d1], 1);
  if (p0 < CAP) slots[(size_t)d0*CAP + p0] = (unsigned short)v0;
  if (p1 < CAP) slots[(size_t)d1*CAP + p1] = (unsigned short)v1;
}

// ------- gather (bf16 embW1) + LN + relu -> bf16 row-major ----------------
// 16 threads per node, 8 cols per thread, fp32 accumulate.
__global__ __launch_bounds__(512) void k_gather(
    const unsigned short* __restrict__ embW1, const int* __restrict__ nf,
    const int* __restrict__ cnt, const unsigned short* __restrict__ slots,
    const float* __restrict__ b1, const float* __restrict__ g1,
    const float* __restrict__ be1,
    unsigned short* __restrict__ xbuf)
{
  const int tid  = threadIdx.x;
  const int node = blockIdx.x*32 + (tid >> 4);
  const int part = tid & 15;                     // cols part*8 .. part*8+7
  const short8* base8 = (const short8*)embW1;    // row stride = 16 short8

  const int self = nf[node];
  int m = cnt[node]; if (m > CAP) m = CAP;
  const unsigned short* sl = slots + (size_t)node*CAP;
  const uint4 sv0 = *(const uint4*)(sl);
  const uint4 sv1 = *(const uint4*)(sl + 8);
  const uint4 sv2 = *(const uint4*)(sl + 16);
  unsigned sw[12] = {sv0.x,sv0.y,sv0.z,sv0.w, sv1.x,sv1.y,sv1.z,sv1.w,
                     sv2.x,sv2.y,sv2.z,sv2.w};

  float a[8];
  {
    const float4* bp = (const float4*)(b1 + part*8);
    float4 x = bp[0], y = bp[1];
    a[0]=x.x; a[1]=x.y; a[2]=x.z; a[3]=x.w;
    a[4]=y.x; a[5]=y.y; a[6]=y.z; a[7]=y.w;
  }
#define ACC8(V) { _Pragma("unroll") \
    for (int i_ = 0; i_ < 8; ++i_) { \
      unsigned uu = ((unsigned)(unsigned short)(V)[i_]) << 16; \
      a[i_] += __builtin_bit_cast(float, uu); } }

  // batch 1: self + neighbors 0..7  (9 independent loads in flight)
  {
    short8 t0 = base8[(size_t)self*16 + part];
    short8 t[8];
    #pragma unroll
    for (int e = 0; e < 8; ++e) {
      unsigned id = (sw[e >> 1] >> ((e & 1)*16)) & 0xffffu;
      int idx = (e < m) ? (int)id : self;
      t[e] = base8[(size_t)idx*16 + part];
    }
    ACC8(t0)
    #pragma unroll
    for (int e = 0; e < 8; ++e) if (e < m) ACC8(t[e])
  }
  if (m > 8) {
    short8 t[8];
    #pragma unroll
    for (int e = 0; e < 8; ++e) {
      unsigned id = (sw[4 + (e >> 1)] >> ((e & 1)*16)) & 0xffffu;
      int idx = (e + 8 < m) ? (int)id : self;
      t[e] = base8[(size_t)idx*16 + part];
    }
    #pragma unroll
    for (int e = 0; e < 8; ++e) if (e + 8 < m) ACC8(t[e])
  }
  if (m > 16) {
    short8 t[8];
    #pragma unroll
    for (int e = 0; e < 8; ++e) {
      unsigned id = (sw[8 + (e >> 1)] >> ((e & 1)*16)) & 0xffffu;
      int idx = (e + 16 < m) ? (int)id : self;
      t[e] = base8[(size_t)idx*16 + part];
    }
    #pragma unroll
    for (int e = 0; e < 8; ++e) if (e + 16 < m) ACC8(t[e])
  }
  for (int e = 24; e < m; ++e) {                 // Poisson(8): ~never
    short8 t = base8[(size_t)sl[e]*16 + part];
    ACC8(t)
  }

  // LayerNorm over the 16-lane group
  float s = 0.f, qs = 0.f;
  #pragma unroll
  for (int i = 0; i < 8; ++i) { s += a[i]; qs += a[i]*a[i]; }
  #pragma unroll
  for (int msk = 1; msk < 16; msk <<= 1) {
    s  += __shfl_xor(s,  msk, 64);
    qs += __shfl_xor(qs, msk, 64);
  }
  const float mean = s * (1.f/128.f);
  const float var  = qs * (1.f/128.f) - mean*mean;
  const float rs   = rsqrtf(var + 1e-5f);
  float gg[8], bb[8];
  {
    const float4* gp = (const float4*)(g1  + part*8);
    const float4* ep = (const float4*)(be1 + part*8);
    float4 g0 = gp[0], g1v = gp[1], e0 = ep[0], e1v = ep[1];
    gg[0]=g0.x; gg[1]=g0.y; gg[2]=g0.z; gg[3]=g0.w;
    gg[4]=g1v.x; gg[5]=g1v.y; gg[6]=g1v.z; gg[7]=g1v.w;
    bb[0]=e0.x; bb[1]=e0.y; bb[2]=e0.z; bb[3]=e0.w;
    bb[4]=e1v.x; bb[5]=e1v.y; bb[6]=e1v.z; bb[7]=e1v.w;
  }
  float v[8];
  #pragma unroll
  for (int i = 0; i < 8; ++i)
    v[i] = fmaxf((a[i] - mean)*rs*gg[i] + bb[i], 0.f);
  uint4 pk;
  pk.x = (unsigned)f2bf(v[0]) | ((unsigned)f2bf(v[1]) << 16);
  pk.y = (unsigned)f2bf(v[2]) | ((unsigned)f2bf(v[3]) << 16);
  pk.z = (unsigned)f2bf(v[4]) | ((unsigned)f2bf(v[5]) << 16);
  pk.w = (unsigned)f2bf(v[6]) | ((unsigned)f2bf(v[7]) << 16);
  *(uint4*)(xbuf + (size_t)node*DIM + part*8) = pk;
}

// ---------------- 3x MFMA stages + final LN (in-place frag-swizzle) --------
// 2048 blocks x 256 thr; each block: 64 node rows.
__global__ __launch_bounds__(256, 4) void k_mlp(
    const unsigned short* __restrict__ wswz,   // [3][4ks][8n][64lane][8j]
    const float* __restrict__ b2,  const float* __restrict__ pb1, const float* __restrict__ pb2,
    const float* __restrict__ ng,  const float* __restrict__ nbv,
    unsigned short* __restrict__ xbuf, float* __restrict__ gsum)
{
  __shared__ unsigned short act[64][136];
  __shared__ float gpart[4][128];
  const int tid   = threadIdx.x;
  const int nbase = blockIdx.x * 64;

  // stage tile global -> LDS (coalesced)
  {
    const short8* src = (const short8*)(xbuf + (size_t)nbase*DIM);
    #pragma unroll
    for (int i = tid; i < 1024; i += 256) {
      int row = i >> 4, c8 = i & 15;
      *(short8*)&act[row][c8*8] = src[i];
    }
  }
  __syncthreads();

  const int wave = tid >> 6, lane = tid & 63;
  const int l15 = lane & 15, lg = lane >> 4;
  const int arow = wave*16 + l15;
  const short8* ws8 = (const short8*)wswz;

  for (int s = 0; s < 3; ++s) {
    f32x4 acc[8];
    #pragma unroll
    for (int n = 0; n < 8; ++n) acc[n] = (f32x4){0.f,0.f,0.f,0.f};
    #pragma unroll
    for (int ks = 0; ks < 4; ++ks) {
      short8 af = *(const short8*)&act[arow][ks*32 + lg*8];
      #pragma unroll
      for (int n = 0; n < 8; ++n) {
        short8 bf = ws8[s*2048 + ks*512 + n*64 + lane];
        acc[n] = __builtin_amdgcn_mfma_f32_16x16x32_bf16(af, bf, acc[n], 0, 0, 0);
      }
    }
    __syncthreads();

    if (s < 2) {
      const float* bias = (s == 0) ? b2 : pb1;
      #pragma unroll
      for (int n = 0; n < 8; ++n) {
        const float bb = bias[n*16 + l15];
        #pragma unroll
        for (int r = 0; r < 4; ++r) {
          float v = acc[n][r] + bb;
          if (s == 1) v = fmaxf(v, 0.f);
          act[wave*16 + lg*4 + r][n*16 + l15] = f2bf(v);
        }
      }
      __syncthreads();
    } else {
      float sr[4] = {0,0,0,0}, qr[4] = {0,0,0,0};
      #pragma unroll
      for (int n = 0; n < 8; ++n) {
        const float bb = pb2[n*16 + l15];
        #pragma unroll
        for (int r = 0; r < 4; ++r) {
          float v = acc[n][r] + bb; acc[n][r] = v;
          sr[r] += v; qr[r] += v*v;
        }
      }
      #pragma unroll
      for (int r = 0; r < 4; ++r) {
        #pragma unroll
        for (int msk = 1; msk < 16; msk <<= 1) {
          sr[r] += __shfl_xor(sr[r], msk, 64);
          qr[r] += __shfl_xor(qr[r], msk, 64);
        }
      }
      float mean[4], rs[4];
      #pragma unroll
      for (int r = 0; r < 4; ++r) {
        mean[r] = sr[r]*(1.f/128.f);
        float var = qr[r]*(1.f/128.f) - mean[r]*mean[r];
        rs[r] = rsqrtf(var + 1e-5f);
      }
      float pc[8];
      #pragma unroll
      for (int n = 0; n < 8; ++n) pc[n] = 0.f;
      #pragma unroll
      for (int n = 0; n < 8; ++n) {
        const int col = n*16 + l15;
        const float gc = ng[col], bc = nbv[col];
        #pragma unroll
        for (int r = 0; r < 4; ++r) {
          float xo = (acc[n][r] - mean[r])*rs[r]*gc + bc;
          act[wave*16 + lg*4 + r][col] = f2bf(xo);
          pc[n] += xo;
        }
      }
      #pragma unroll
      for (int n = 0; n < 8; ++n) {
        pc[n] += __shfl_xor(pc[n], 16, 64);
        pc[n] += __shfl_xor(pc[n], 32, 64);
      }
      if (lane < 16) {
        #pragma unroll
        for (int n = 0; n < 8; ++n) gpart[wave][n*16 + lane] = pc[n];
      }
      __syncthreads();
      if (tid < 128) {
        float s2 = gpart[0][tid] + gpart[1][tid] + gpart[2][tid] + gpart[3][tid];
        atomicAdd(&gsum[(blockIdx.x >> 3)*DIM + tid], s2);
      }
      // frag-swizzled store (in place over this block's own row range)
      {
        short8* xs8 = (short8*)xbuf;
        #pragma unroll
        for (int i = tid; i < 1024; i += 256) {
          int rowgrp = i >> 8, rem = i & 255;
          int kc = rem >> 4, lv = rem & 15;
          short8 v = *(const short8*)&act[rowgrp*16 + lv][kc*8];
          xs8[((size_t)(nbase >> 4) + rowgrp)*256 + kc*16 + lv] = v;
        }
      }
    }
  }
}

// ------- batched X X^T + packed triu write, with exit-MLP tail blocks ------
__global__ __launch_bounds__(256) void k_scores(const unsigned short* __restrict__ xswz,
    const float* __restrict__ gsum,
    const float* __restrict__ eW1, const float* __restrict__ eb1,
    const float* __restrict__ eg,  const float* __restrict__ ebe,
    const float* __restrict__ eW2, const float* __restrict__ eb2,
    float* __restrict__ out)
{
  const int tid = threadIdx.x;

  if (blockIdx.x >= 2560) {
    // exit MLP: 2 graphs per block (128 threads each)
    __shared__ float mrow[2][DIM];
    __shared__ float red[2][2][2];
    __shared__ float red2[2][2];
    const int grp = tid >> 7;                 // 0/1
    const int t   = tid & 127;
    const int gi  = ((int)blockIdx.x - 2560)*2 + grp;
    mrow[grp][t] = gsum[gi*DIM + t] * (1.f/512.f);
    __syncthreads();
    float u = eb1[t];
    #pragma unroll 8
    for (int k = 0; k < DIM; ++k) u = fmaf(mrow[grp][k], eW1[k*DIM + t], u);
    float s = u, q = u*u;
    #pragma unroll
    for (int m = 1; m < 64; m <<= 1) { s += __shfl_xor(s, m, 64); q += __shfl_xor(q, m, 64); }
    const int wv = (tid >> 6) & 1;
    if ((tid & 63) == 0) { red[grp][wv][0] = s; red[grp][wv][1] = q; }
    __syncthreads();
    const float S = red[grp][0][0] + red[grp][1][0];
    const float Q = red[grp][0][1] + red[grp][1][1];
    const float mean = S*(1.f/128.f);
    const float var  = Q*(1.f/128.f) - mean*mean;
    float av = fmaxf((u - mean)*rsqrtf(var + 1e-5f)*eg[t] + ebe[t], 0.f);
    float p = av * eW2[t];
    #pragma unroll
    for (int m = 1; m < 64; m <<= 1) p += __shfl_xor(p, m, 64);
    if ((tid & 63) == 0) red2[grp][wv] = p;
    __syncthreads();
    if (t == 0) {
      float e = red2[grp][0] + red2[grp][1] + eb2[0];
      out[gi*3 + 1] = 1.f - e;
      out[gi*3 + 2] = e;
    }
    return;
  }

  static const int TI[10] = {0,0,0,0,1,1,1,2,2,3};
  static const int TJ[10] = {0,1,2,3,1,2,3,2,3,3};
  const int b = blockIdx.x / 10, p = blockIdx.x % 10;
  const int ti = TI[p], tj = TJ[p];
  const int wave = tid >> 6, lane = tid & 63;
  const int l15 = lane & 15, lg = lane >> 4;
  const short8* Xs = (const short8*)xswz + (size_t)b*8192;  // 512*128/8

  f32x4 acc0[8], acc1[8];
  #pragma unroll
  for (int n = 0; n < 8; ++n) { acc0[n] = (f32x4){0,0,0,0}; acc1[n] = (f32x4){0,0,0,0}; }

  #pragma unroll
  for (int ks = 0; ks < 4; ++ks) {
    const int kq = ks*4 + lg;
    short8 a0 = Xs[(size_t)(ti*8 + wave*2 + 0)*256 + kq*16 + l15];
    short8 a1 = Xs[(size_t)(ti*8 + wave*2 + 1)*256 + kq*16 + l15];
    #pragma unroll
    for (int n = 0; n < 8; ++n) {
      short8 bf = Xs[(size_t)(tj*8 + n)*256 + kq*16 + l15];
      acc0[n] = __builtin_amdgcn_mfma_f32_16x16x32_bf16(a0, bf, acc0[n], 0, 0, 0);
      acc1[n] = __builtin_amdgcn_mfma_f32_16x16x32_bf16(a1, bf, acc1[n], 0, 0, 0);
    }
  }

  const float scale = 0.08838834764831845f;   // 1/sqrt(128)
  float* ea = out + 3072 + (size_t)b*EPB;
  #pragma unroll
  for (int m = 0; m < 2; ++m) {
    #pragma unroll
    for (int n = 0; n < 8; ++n) {
      const int gj = tj*128 + n*16 + l15;
      #pragma unroll
      for (int r = 0; r < 4; ++r) {
        const int gi = ti*128 + wave*32 + m*16 + lg*4 + r;
        if (gi < gj) {
          const int rowbase = gi*511 - (gi*(gi-1))/2 - gi - 1;
          const float v = (m == 0) ? acc0[n][r] : acc1[n][r];
          ea[rowbase + gj] = v * scale;
        }
      }
    }
  }
}

extern "C" void kernel_launch(void* const* d_in, const int* in_sizes, int n_in,
                              void* d_out, int out_size, void* d_ws, size_t ws_size,
                              hipStream_t stream) {
  const int*   nf   = (const int*)d_in[0];
  const int*   ei   = (const int*)d_in[1];
  const float* emb  = (const float*)d_in[3];
  const float* gW1  = (const float*)d_in[4];
  const float* gb1  = (const float*)d_in[5];
  const float* gg1  = (const float*)d_in[6];
  const float* gbe1 = (const float*)d_in[7];
  const float* gW2  = (const float*)d_in[8];
  const float* gb2  = (const float*)d_in[9];
  const float* pW1  = (const float*)d_in[10];
  const float* pb1  = (const float*)d_in[11];
  const float* pW2  = (const float*)d_in[12];
  const float* pb2  = (const float*)d_in[13];
  const float* ng   = (const float*)d_in[14];
  const float* nb   = (const float*)d_in[15];
  const float* eW1  = (const float*)d_in[16];
  const float* eb1  = (const float*)d_in[17];
  const float* eg   = (const float*)d_in[18];
  const float* ebe  = (const float*)d_in[19];
  const float* eW2  = (const float*)d_in[20];
  const float* eb2  = (const float*)d_in[21];
  float* out = (float*)d_out;

  char* ws = (char*)d_ws;
  unsigned short* embW1 = (unsigned short*)ws;                 // 131072 B used (262144 reserved)
  unsigned short* wswz  = (unsigned short*)(ws + 262144);      // 98304 B
  int*            cnt   = (int*)(ws + 360448);                 // 524288 B
  unsigned short* slots = (unsigned short*)(ws + 884736);      // 12582912 B
  unsigned short* xbuf  = (unsigned short*)(ws + 13467648);    // 33554432 B
  float*          gsum  = (float*)(ws + 47022080);             // 131072 B
  if (ws_size < 47153152) return;

  k_prep  <<<1100, 256, 0, stream>>>(emb, gW1, embW1, gW2, pW1, pW2, wswz,
                                     cnt, gsum, out);
  k_edges <<<2048, 256, 0, stream>>>(ei, nf, cnt, slots);
  k_gather<<<4096, 512, 0, stream>>>(embW1, nf, cnt, slots, gb1, gg1, gbe1, xbuf);
  k_mlp   <<<2048, 256, 0, stream>>>(wswz, gb2, pb1, pb2, ng, nb, xbuf, gsum);
  k_scores<<<2688, 256, 0, stream>>>(xbuf, gsum, eW1, eb1, eg, ebe, eW2, eb2, out);
}

// Round 6
// 183.641 us; speedup vs baseline: 1.9770x; 1.0792x over previous
//
#include <hip/hip_runtime.h>
#include <hip/hip_bf16.h>

#define NBATCH 256
#define NNODES 512
#define DIM    128
#define NTOT   (NBATCH*NNODES)   // 131072
#define NEDGE  (NTOT*8)          // 1048576
#define EPB    130816            // NNODES*(NNODES-1)/2
#define CAP    48

typedef __attribute__((ext_vector_type(8))) short  short8;
typedef __attribute__((ext_vector_type(4))) float  f32x4;

__device__ __forceinline__ unsigned short f2bf(float f){
  unsigned u = __builtin_bit_cast(unsigned, f);
  unsigned r = u + 0x7FFFu + ((u >> 16) & 1u);   // RNE
  return (unsigned short)(r >> 16);
}

// ---- fused prep: embW1 GEMM (bf16 out) + weight frag-swizzle + zeroing ----
__global__ __launch_bounds__(256) void k_prep(
    const float* __restrict__ emb, const float* __restrict__ W1,
    unsigned short* __restrict__ embW1,
    const float* __restrict__ W2, const float* __restrict__ P1,
    const float* __restrict__ P2, unsigned short* __restrict__ wswz,
    int* __restrict__ cnt, float* __restrict__ gsum, float* __restrict__ out)
{
  const int tid = threadIdx.x;
  const int blk = blockIdx.x;
  __shared__ float er[2][DIM];
  if (blk < 256) {
    const int half = tid >> 7, c = tid & 127;
    const int r = blk*2 + half;
    er[half][c] = emb[r*DIM + c];
    __syncthreads();
    float acc = 0.f;
    #pragma unroll 8
    for (int k = 0; k < DIM; ++k) acc = fmaf(er[half][k], W1[k*DIM + c], acc);
    embW1[r*DIM + c] = f2bf(acc);
  } else if (blk < 448) {
    int idx = (blk - 256)*256 + tid;               // 49152 total
    int s = idx >> 14, rem = idx & 16383;
    int ks = rem >> 12, n = (rem >> 9) & 7, lane = (rem >> 3) & 63, j = rem & 7;
    int lg = lane >> 4, l15 = lane & 15;
    int k = ks*32 + lg*8 + j, c = n*16 + l15;
    const float* src = (s == 0) ? W2 : ((s == 1) ? P1 : P2);
    wswz[idx] = f2bf(src[k*DIM + c]);
  } else {
    int idx = (blk - 448)*256 + tid;               // 166912 total, exact
    if (idx < NTOT)                cnt[idx] = 0;
    else if (idx < NTOT + 32768)   gsum[idx - NTOT] = 0.f;
    else                           out[idx - NTOT - 32768] = 0.f;
  }
}

// ---------------- edge scatter, 2 edges per thread ----------------
__global__ __launch_bounds__(256) void k_edges(const int* __restrict__ ei,
                                               const int* __restrict__ nf,
                                               int* __restrict__ cnt,
                                               unsigned short* __restrict__ slots){
  int e0 = blockIdx.x*512 + threadIdx.x;
  int e1 = e0 + 256;
  int s0 = ei[e0],        s1 = ei[e1];
  int d0 = ei[NEDGE + e0], d1 = ei[NEDGE + e1];
  int v0 = nf[s0],        v1 = nf[s1];
  int p0 = atomicAdd(&cnt[d0], 1);
  int p1 = atomicAdd(&cnt[d1], 1);
  if (p0 < CAP) slots[(size_t)d0*CAP + p0] = (unsigned short)v0;
  if (p1 < CAP) slots[(size_t)d1*CAP + p1] = (unsigned short)v1;
}

// ------ fused gather + LN + relu + 3x MFMA MLP + final LN + swizzle -------
// 4096 blocks x 512 thr; 32 nodes per block (16 threads/node gather shape).
__global__ __launch_bounds__(512, 4) void k_gnn(
    const unsigned short* __restrict__ embW1, const int* __restrict__ nf,
    const int* __restrict__ cnt, const unsigned short* __restrict__ slots,
    const float* __restrict__ b1, const float* __restrict__ g1,
    const float* __restrict__ be1,
    const unsigned short* __restrict__ wswz,   // [3][4ks][8n][64lane][8j]
    const float* __restrict__ b2,  const float* __restrict__ pb1, const float* __restrict__ pb2,
    const float* __restrict__ ng,  const float* __restrict__ nbv,
    unsigned short* __restrict__ xbuf, float* __restrict__ gsum)
{
  __shared__ unsigned short act[32][136];     // +8 pad
  __shared__ float rpart[4][32][2];
  __shared__ float rfin[32][2];
  __shared__ float gpart[8][128];
  const int tid   = threadIdx.x;
  const int nbase = blockIdx.x * 32;

  // ---------------- gather phase (16 thr/node, bf16 embW1) ----------------
  {
    const int node = nbase + (tid >> 4);
    const int part = tid & 15;
    const short8* base8 = (const short8*)embW1;

    const int self = nf[node];
    int m = cnt[node]; if (m > CAP) m = CAP;
    const unsigned short* sl = slots + (size_t)node*CAP;
    const uint4 sv0 = *(const uint4*)(sl);
    const uint4 sv1 = *(const uint4*)(sl + 8);
    const uint4 sv2 = *(const uint4*)(sl + 16);
    unsigned sw[12] = {sv0.x,sv0.y,sv0.z,sv0.w, sv1.x,sv1.y,sv1.z,sv1.w,
                       sv2.x,sv2.y,sv2.z,sv2.w};

    float a[8];
    {
      const float4* bp = (const float4*)(b1 + part*8);
      float4 x = bp[0], y = bp[1];
      a[0]=x.x; a[1]=x.y; a[2]=x.z; a[3]=x.w;
      a[4]=y.x; a[5]=y.y; a[6]=y.z; a[7]=y.w;
    }
#define ACC8(V) { _Pragma("unroll") \
    for (int i_ = 0; i_ < 8; ++i_) { \
      unsigned uu = ((unsigned)(unsigned short)(V)[i_]) << 16; \
      a[i_] += __builtin_bit_cast(float, uu); } }

    {
      short8 t0 = base8[(size_t)self*16 + part];
      short8 t[8];
      #pragma unroll
      for (int e = 0; e < 8; ++e) {
        unsigned id = (sw[e >> 1] >> ((e & 1)*16)) & 0xffffu;
        int idx = (e < m) ? (int)id : self;
        t[e] = base8[(size_t)idx*16 + part];
      }
      ACC8(t0)
      #pragma unroll
      for (int e = 0; e < 8; ++e) if (e < m) ACC8(t[e])
    }
    if (m > 8) {
      short8 t[8];
      #pragma unroll
      for (int e = 0; e < 8; ++e) {
        unsigned id = (sw[4 + (e >> 1)] >> ((e & 1)*16)) & 0xffffu;
        int idx = (e + 8 < m) ? (int)id : self;
        t[e] = base8[(size_t)idx*16 + part];
      }
      #pragma unroll
      for (int e = 0; e < 8; ++e) if (e + 8 < m) ACC8(t[e])
    }
    if (m > 16) {
      short8 t[8];
      #pragma unroll
      for (int e = 0; e < 8; ++e) {
        unsigned id = (sw[8 + (e >> 1)] >> ((e & 1)*16)) & 0xffffu;
        int idx = (e + 16 < m) ? (int)id : self;
        t[e] = base8[(size_t)idx*16 + part];
      }
      #pragma unroll
      for (int e = 0; e < 8; ++e) if (e + 16 < m) ACC8(t[e])
    }
    for (int e = 24; e < m; ++e) {
      short8 t = base8[(size_t)sl[e]*16 + part];
      ACC8(t)
    }

    float s = 0.f, qs = 0.f;
    #pragma unroll
    for (int i = 0; i < 8; ++i) { s += a[i]; qs += a[i]*a[i]; }
    #pragma unroll
    for (int msk = 1; msk < 16; msk <<= 1) {
      s  += __shfl_xor(s,  msk, 64);
      qs += __shfl_xor(qs, msk, 64);
    }
    const float mean = s * (1.f/128.f);
    const float var  = qs * (1.f/128.f) - mean*mean;
    const float rs   = rsqrtf(var + 1e-5f);
    float gg[8], bb[8];
    {
      const float4* gp = (const float4*)(g1  + part*8);
      const float4* ep = (const float4*)(be1 + part*8);
      float4 g0 = gp[0], g1v = gp[1], e0 = ep[0], e1v = ep[1];
      gg[0]=g0.x; gg[1]=g0.y; gg[2]=g0.z; gg[3]=g0.w;
      gg[4]=g1v.x; gg[5]=g1v.y; gg[6]=g1v.z; gg[7]=g1v.w;
      bb[0]=e0.x; bb[1]=e0.y; bb[2]=e0.z; bb[3]=e0.w;
      bb[4]=e1v.x; bb[5]=e1v.y; bb[6]=e1v.z; bb[7]=e1v.w;
    }
    float v[8];
    #pragma unroll
    for (int i = 0; i < 8; ++i)
      v[i] = fmaxf((a[i] - mean)*rs*gg[i] + bb[i], 0.f);
    uint4 pk;
    pk.x = (unsigned)f2bf(v[0]) | ((unsigned)f2bf(v[1]) << 16);
    pk.y = (unsigned)f2bf(v[2]) | ((unsigned)f2bf(v[3]) << 16);
    pk.z = (unsigned)f2bf(v[4]) | ((unsigned)f2bf(v[5]) << 16);
    pk.w = (unsigned)f2bf(v[6]) | ((unsigned)f2bf(v[7]) << 16);
    *(uint4*)&act[tid >> 4][part*8] = pk;
  }
  __syncthreads();

  // ---------------- MFMA phase: 8 waves, wave = nb*2 + rt ----------------
  const int wave = tid >> 6, lane = tid & 63;
  const int l15 = lane & 15, lg = lane >> 4;
  const int rt = wave & 1, nb = wave >> 1;
  const int arow = rt*16 + l15;
  const short8* ws8 = (const short8*)wswz;

  for (int s = 0; s < 3; ++s) {
    f32x4 acc0 = (f32x4){0.f,0.f,0.f,0.f};
    f32x4 acc1 = (f32x4){0.f,0.f,0.f,0.f};
    #pragma unroll
    for (int ks = 0; ks < 4; ++ks) {
      short8 af  = *(const short8*)&act[arow][ks*32 + lg*8];
      short8 bf0 = ws8[s*2048 + ks*512 + (nb*2 + 0)*64 + lane];
      short8 bf1 = ws8[s*2048 + ks*512 + (nb*2 + 1)*64 + lane];
      acc0 = __builtin_amdgcn_mfma_f32_16x16x32_bf16(af, bf0, acc0, 0, 0, 0);
      acc1 = __builtin_amdgcn_mfma_f32_16x16x32_bf16(af, bf1, acc1, 0, 0, 0);
    }
    __syncthreads();   // all act reads done before overwrite

    if (s < 2) {
      const float* bias = (s == 0) ? b2 : pb1;
      const float bb0 = bias[nb*32 + l15], bb1 = bias[nb*32 + 16 + l15];
      #pragma unroll
      for (int q = 0; q < 4; ++q) {
        float x0 = acc0[q] + bb0, x1 = acc1[q] + bb1;
        if (s == 1) { x0 = fmaxf(x0, 0.f); x1 = fmaxf(x1, 0.f); }
        act[rt*16 + lg*4 + q][nb*32 + l15]      = f2bf(x0);
        act[rt*16 + lg*4 + q][nb*32 + 16 + l15] = f2bf(x1);
      }
      __syncthreads();
    } else {
      // ---- final LN: cross-wave row reduction via LDS ----
      const float bb0 = pb2[nb*32 + l15], bb1 = pb2[nb*32 + 16 + l15];
      float w0v[4], w1v[4], sr[4], qr[4];
      #pragma unroll
      for (int q = 0; q < 4; ++q) {
        float x0 = acc0[q] + bb0, x1 = acc1[q] + bb1;
        w0v[q] = x0; w1v[q] = x1;
        sr[q] = x0 + x1; qr[q] = x0*x0 + x1*x1;
      }
      #pragma unroll
      for (int msk = 1; msk < 16; msk <<= 1) {
        #pragma unroll
        for (int q = 0; q < 4; ++q) {
          sr[q] += __shfl_xor(sr[q], msk, 64);
          qr[q] += __shfl_xor(qr[q], msk, 64);
        }
      }
      if (l15 == 0) {
        #pragma unroll
        for (int q = 0; q < 4; ++q) {
          rpart[nb][rt*16 + lg*4 + q][0] = sr[q];
          rpart[nb][rt*16 + lg*4 + q][1] = qr[q];
        }
      }
      __syncthreads();
      if (tid < 64) {
        int row = tid >> 1, vv = tid & 1;
        rfin[row][vv] = rpart[0][row][vv] + rpart[1][row][vv]
                      + rpart[2][row][vv] + rpart[3][row][vv];
      }
      __syncthreads();
      const int c0 = nb*32 + l15, c1 = c0 + 16;
      const float gc0 = ng[c0], gc1 = ng[c1], bc0 = nbv[c0], bc1 = nbv[c1];
      float pc0 = 0.f, pc1 = 0.f;
      #pragma unroll
      for (int q = 0; q < 4; ++q) {
        const int row = rt*16 + lg*4 + q;
        const float mean = rfin[row][0]*(1.f/128.f);
        const float var  = rfin[row][1]*(1.f/128.f) - mean*mean;
        const float rs   = rsqrtf(var + 1e-5f);
        float x0 = (w0v[q] - mean)*rs*gc0 + bc0;
        float x1 = (w1v[q] - mean)*rs*gc1 + bc1;
        act[row][c0] = f2bf(x0);
        act[row][c1] = f2bf(x1);
        pc0 += x0; pc1 += x1;
      }
      pc0 += __shfl_xor(pc0, 16, 64); pc0 += __shfl_xor(pc0, 32, 64);
      pc1 += __shfl_xor(pc1, 16, 64); pc1 += __shfl_xor(pc1, 32, 64);
      if (lg == 0) { gpart[wave][c0] = pc0; gpart[wave][c1] = pc1; }
      __syncthreads();
      if (tid < 128) {
        const int w0 = (tid >> 5)*2;
        float s2 = gpart[w0][tid] + gpart[w0 + 1][tid];
        atomicAdd(&gsum[(blockIdx.x >> 4)*DIM + tid], s2);
      }
      // frag-swizzled xbuf store (rows of this block only)
      {
        short8* xs8 = (short8*)xbuf;
        const int i = tid;                 // 512 = 2 rowgrps * 16 kc * 16 lv
        const int rowgrp = i >> 8, rem = i & 255;
        const int kc = rem >> 4, lv = rem & 15;
        short8 vv = *(const short8*)&act[rowgrp*16 + lv][kc*8];
        xs8[((size_t)(nbase >> 4) + rowgrp)*256 + kc*16 + lv] = vv;
      }
    }
  }
}

// ------- batched X X^T + packed triu write, with exit-MLP tail blocks ------
// tile blocks: b = blk & 255, p = blk >> 8  => all 10 tiles of batch b land
// on XCD b%8 (round-robin dispatch); each XCD's 32 batches = 4MB = its L2.
__global__ __launch_bounds__(256) void k_scores(const unsigned short* __restrict__ xswz,
    const float* __restrict__ gsum,
    const float* __restrict__ eW1, const float* __restrict__ eb1,
    const float* __restrict__ eg,  const float* __restrict__ ebe,
    const float* __restrict__ eW2, const float* __restrict__ eb2,
    float* __restrict__ out)
{
  const int tid = threadIdx.x;

  if (blockIdx.x >= 2560) {
    // exit MLP: 2 graphs per block (128 threads each)
    __shared__ float mrow[2][DIM];
    __shared__ float red[2][2][2];
    __shared__ float red2[2][2];
    const int grp = tid >> 7;
    const int t   = tid & 127;
    const int gi  = ((int)blockIdx.x - 2560)*2 + grp;
    mrow[grp][t] = gsum[gi*DIM + t] * (1.f/512.f);
    __syncthreads();
    float u = eb1[t];
    #pragma unroll 8
    for (int k = 0; k < DIM; ++k) u = fmaf(mrow[grp][k], eW1[k*DIM + t], u);
    float s = u, q = u*u;
    #pragma unroll
    for (int m = 1; m < 64; m <<= 1) { s += __shfl_xor(s, m, 64); q += __shfl_xor(q, m, 64); }
    const int wv = (tid >> 6) & 1;
    if ((tid & 63) == 0) { red[grp][wv][0] = s; red[grp][wv][1] = q; }
    __syncthreads();
    const float S = red[grp][0][0] + red[grp][1][0];
    const float Q = red[grp][0][1] + red[grp][1][1];
    const float mean = S*(1.f/128.f);
    const float var  = Q*(1.f/128.f) - mean*mean;
    float av = fmaxf((u - mean)*rsqrtf(var + 1e-5f)*eg[t] + ebe[t], 0.f);
    float p = av * eW2[t];
    #pragma unroll
    for (int m = 1; m < 64; m <<= 1) p += __shfl_xor(p, m, 64);
    if ((tid & 63) == 0) red2[grp][wv] = p;
    __syncthreads();
    if (t == 0) {
      float e = red2[grp][0] + red2[grp][1] + eb2[0];
      out[gi*3 + 1] = 1.f - e;
      out[gi*3 + 2] = e;
    }
    return;
  }

  static const int TI[10] = {0,0,0,0,1,1,1,2,2,3};
  static const int TJ[10] = {0,1,2,3,1,2,3,2,3,3};
  const int b = blockIdx.x & 255, p = blockIdx.x >> 8;
  const int ti = TI[p], tj = TJ[p];
  const int wave = tid >> 6, lane = tid & 63;
  const int l15 = lane & 15, lg = lane >> 4;
  const short8* Xs = (const short8*)xswz + (size_t)b*8192;  // 512*128/8

  f32x4 acc0[8], acc1[8];
  #pragma unroll
  for (int n = 0; n < 8; ++n) { acc0[n] = (f32x4){0,0,0,0}; acc1[n] = (f32x4){0,0,0,0}; }

  #pragma unroll
  for (int ks = 0; ks < 4; ++ks) {
    const int kq = ks*4 + lg;
    short8 a0 = Xs[(size_t)(ti*8 + wave*2 + 0)*256 + kq*16 + l15];
    short8 a1 = Xs[(size_t)(ti*8 + wave*2 + 1)*256 + kq*16 + l15];
    #pragma unroll
    for (int n = 0; n < 8; ++n) {
      short8 bf = Xs[(size_t)(tj*8 + n)*256 + kq*16 + l15];
      acc0[n] = __builtin_amdgcn_mfma_f32_16x16x32_bf16(a0, bf, acc0[n], 0, 0, 0);
      acc1[n] = __builtin_amdgcn_mfma_f32_16x16x32_bf16(a1, bf, acc1[n], 0, 0, 0);
    }
  }

  const float scale = 0.08838834764831845f;   // 1/sqrt(128)
  float* ea = out + 3072 + (size_t)b*EPB;
  #pragma unroll
  for (int m = 0; m < 2; ++m) {
    #pragma unroll
    for (int n = 0; n < 8; ++n) {
      const int gj = tj*128 + n*16 + l15;
      #pragma unroll
      for (int r = 0; r < 4; ++r) {
        const int gi = ti*128 + wave*32 + m*16 + lg*4 + r;
        if (gi < gj) {
          const int rowbase = gi*511 - (gi*(gi-1))/2 - gi - 1;
          const float v = (m == 0) ? acc0[n][r] : acc1[n][r];
          ea[rowbase + gj] = v * scale;
        }
      }
    }
  }
}

extern "C" void kernel_launch(void* const* d_in, const int* in_sizes, int n_in,
                              void* d_out, int out_size, void* d_ws, size_t ws_size,
                              hipStream_t stream) {
  const int*   nf   = (const int*)d_in[0];
  const int*   ei   = (const int*)d_in[1];
  const float* emb  = (const float*)d_in[3];
  const float* gW1  = (const float*)d_in[4];
  const float* gb1  = (const float*)d_in[5];
  const float* gg1  = (const float*)d_in[6];
  const float* gbe1 = (const float*)d_in[7];
  const float* gW2  = (const float*)d_in[8];
  const float* gb2  = (const float*)d_in[9];
  const float* pW1  = (const float*)d_in[10];
  const float* pb1  = (const float*)d_in[11];
  const float* pW2  = (const float*)d_in[12];
  const float* pb2  = (const float*)d_in[13];
  const float* ng   = (const float*)d_in[14];
  const float* nb   = (const float*)d_in[15];
  const float* eW1  = (const float*)d_in[16];
  const float* eb1  = (const float*)d_in[17];
  const float* eg   = (const float*)d_in[18];
  const float* ebe  = (const float*)d_in[19];
  const float* eW2  = (const float*)d_in[20];
  const float* eb2  = (const float*)d_in[21];
  float* out = (float*)d_out;

  char* ws = (char*)d_ws;
  unsigned short* embW1 = (unsigned short*)ws;                 // 131072 B used
  unsigned short* wswz  = (unsigned short*)(ws + 262144);      // 98304 B
  int*            cnt   = (int*)(ws + 360448);                 // 524288 B
  unsigned short* slots = (unsigned short*)(ws + 884736);      // 12582912 B
  unsigned short* xbuf  = (unsigned short*)(ws + 13467648);    // 33554432 B
  float*          gsum  = (float*)(ws + 47022080);             // 131072 B
  if (ws_size < 47153152) return;

  k_prep  <<<1100, 256, 0, stream>>>(emb, gW1, embW1, gW2, pW1, pW2, wswz,
                                     cnt, gsum, out);
  k_edges <<<2048, 256, 0, stream>>>(ei, nf, cnt, slots);
  k_gnn   <<<4096, 512, 0, stream>>>(embW1, nf, cnt, slots, gb1, gg1, gbe1,
                                     wswz, gb2, pb1, pb2, ng, nb, xbuf, gsum);
  k_scores<<<2688, 256, 0, stream>>>(xbuf, gsum, eW1, eb1, eg, ebe, eW2, eb2, out);
}

// Round 7
// 164.867 us; speedup vs baseline: 2.2021x; 1.1139x over previous
//
#include <hip/hip_runtime.h>
#include <hip/hip_bf16.h>

#define NBATCH 256
#define NNODES 512
#define DIM    128
#define NTOT   (NBATCH*NNODES)   // 131072
#define NEDGE  (NTOT*8)          // 1048576
#define EPB    130816            // NNODES*(NNODES-1)/2
#define CAP    32

typedef __attribute__((ext_vector_type(8))) short  short8;
typedef __attribute__((ext_vector_type(4))) float  f32x4;

__device__ __forceinline__ unsigned short f2bf(float f){
  unsigned u = __builtin_bit_cast(unsigned, f);
  unsigned r = u + 0x7FFFu + ((u >> 16) & 1u);   // RNE
  return (unsigned short)(r >> 16);
}

// ---- fused prep: embW1 GEMM (bf16 out) + weight frag-swizzle + zeroing ----
__global__ __launch_bounds__(256) void k_prep(
    const float* __restrict__ emb, const float* __restrict__ W1,
    unsigned short* __restrict__ embW1,
    const float* __restrict__ W2, const float* __restrict__ P1,
    const float* __restrict__ P2, unsigned short* __restrict__ wswz,
    int* __restrict__ cnt, float* __restrict__ gsum, float* __restrict__ out)
{
  const int tid = threadIdx.x;
  const int blk = blockIdx.x;
  __shared__ float er[2][DIM];
  if (blk < 256) {
    const int half = tid >> 7, c = tid & 127;
    const int r = blk*2 + half;
    er[half][c] = emb[r*DIM + c];
    __syncthreads();
    float acc = 0.f;
    #pragma unroll 8
    for (int k = 0; k < DIM; ++k) acc = fmaf(er[half][k], W1[k*DIM + c], acc);
    embW1[r*DIM + c] = f2bf(acc);
  } else if (blk < 448) {
    int idx = (blk - 256)*256 + tid;               // 49152 total
    int s = idx >> 14, rem = idx & 16383;
    int ks = rem >> 12, n = (rem >> 9) & 7, lane = (rem >> 3) & 63, j = rem & 7;
    int lg = lane >> 4, l15 = lane & 15;
    int k = ks*32 + lg*8 + j, c = n*16 + l15;
    const float* src = (s == 0) ? W2 : ((s == 1) ? P1 : P2);
    wswz[idx] = f2bf(src[k*DIM + c]);
  } else {
    int idx = (blk - 448)*256 + tid;               // 166912 total, exact
    if (idx < NTOT)                cnt[idx] = 0;
    else if (idx < NTOT + 32768)   gsum[idx - NTOT] = 0.f;
    else                           out[idx - NTOT - 32768] = 0.f;
  }
}

// ------- edge scatter, dst-range partitioned (XCD-local atomics/stores) ----
// 2048 blocks = 256 chunks x 8 ranges; block handles chunk (blk>>3), keeps
// edges with dst>>14 == (blk&7). Every edge processed exactly once under ANY
// block->XCD mapping; with round-robin dispatch each range's cnt/slots slice
// stays in one XCD's L2.
__global__ __launch_bounds__(256) void k_edges(const int* __restrict__ ei,
                                               const int* __restrict__ nf,
                                               int* __restrict__ cnt,
                                               unsigned short* __restrict__ slots){
  const int base = (blockIdx.x >> 3)*4096 + threadIdx.x;
  const int r    = blockIdx.x & 7;
  #pragma unroll
  for (int it = 0; it < 16; ++it) {
    const int e = base + it*256;
    const int d = ei[NEDGE + e];
    if ((d >> 14) == r) {
      const int s = ei[e];
      const int v = nf[s];
      const int pos = atomicAdd(&cnt[d], 1);
      if (pos < CAP) slots[(size_t)d*CAP + pos] = (unsigned short)v;
    }
  }
}

// ------ fused gather + LN + relu + 3x MFMA MLP + final LN + swizzle -------
// 4096 blocks x 512 thr; 32 nodes per block (16 threads/node gather shape).
__global__ __launch_bounds__(512, 4) void k_gnn(
    const unsigned short* __restrict__ embW1, const int* __restrict__ nf,
    const int* __restrict__ cnt, const unsigned short* __restrict__ slots,
    const float* __restrict__ b1, const float* __restrict__ g1,
    const float* __restrict__ be1,
    const unsigned short* __restrict__ wswz,   // [3][4ks][8n][64lane][8j]
    const float* __restrict__ b2,  const float* __restrict__ pb1, const float* __restrict__ pb2,
    const float* __restrict__ ng,  const float* __restrict__ nbv,
    unsigned short* __restrict__ xbuf, float* __restrict__ gsum)
{
  __shared__ unsigned short act[32][136];     // +8 pad
  __shared__ float rpart[4][32][2];
  __shared__ float rfin[32][2];
  __shared__ float gpart[8][128];
  const int tid   = threadIdx.x;
  const int nbase = blockIdx.x * 32;

  // ---------------- gather phase (16 thr/node, bf16 embW1) ----------------
  {
    const int node = nbase + (tid >> 4);
    const int part = tid & 15;
    const short8* base8 = (const short8*)embW1;

    const int self = nf[node];
    int m = cnt[node]; if (m > CAP) m = CAP;
    const unsigned short* sl = slots + (size_t)node*CAP;
    const uint4 sv0 = *(const uint4*)(sl);
    const uint4 sv1 = *(const uint4*)(sl + 8);
    const uint4 sv2 = *(const uint4*)(sl + 16);
    unsigned sw[12] = {sv0.x,sv0.y,sv0.z,sv0.w, sv1.x,sv1.y,sv1.z,sv1.w,
                       sv2.x,sv2.y,sv2.z,sv2.w};

    float a[8];
    {
      const float4* bp = (const float4*)(b1 + part*8);
      float4 x = bp[0], y = bp[1];
      a[0]=x.x; a[1]=x.y; a[2]=x.z; a[3]=x.w;
      a[4]=y.x; a[5]=y.y; a[6]=y.z; a[7]=y.w;
    }
#define ACC8(V) { _Pragma("unroll") \
    for (int i_ = 0; i_ < 8; ++i_) { \
      unsigned uu = ((unsigned)(unsigned short)(V)[i_]) << 16; \
      a[i_] += __builtin_bit_cast(float, uu); } }

    {
      short8 t0 = base8[(size_t)self*16 + part];
      short8 t[8];
      #pragma unroll
      for (int e = 0; e < 8; ++e) {
        unsigned id = (sw[e >> 1] >> ((e & 1)*16)) & 0xffffu;
        int idx = (e < m) ? (int)id : self;
        t[e] = base8[(size_t)idx*16 + part];
      }
      ACC8(t0)
      #pragma unroll
      for (int e = 0; e < 8; ++e) if (e < m) ACC8(t[e])
    }
    if (m > 8) {
      short8 t[8];
      #pragma unroll
      for (int e = 0; e < 8; ++e) {
        unsigned id = (sw[4 + (e >> 1)] >> ((e & 1)*16)) & 0xffffu;
        int idx = (e + 8 < m) ? (int)id : self;
        t[e] = base8[(size_t)idx*16 + part];
      }
      #pragma unroll
      for (int e = 0; e < 8; ++e) if (e + 8 < m) ACC8(t[e])
    }
    if (m > 16) {
      short8 t[8];
      #pragma unroll
      for (int e = 0; e < 8; ++e) {
        unsigned id = (sw[8 + (e >> 1)] >> ((e & 1)*16)) & 0xffffu;
        int idx = (e + 16 < m) ? (int)id : self;
        t[e] = base8[(size_t)idx*16 + part];
      }
      #pragma unroll
      for (int e = 0; e < 8; ++e) if (e + 16 < m) ACC8(t[e])
    }
    for (int e = 24; e < m; ++e) {
      short8 t = base8[(size_t)sl[e]*16 + part];
      ACC8(t)
    }

    float s = 0.f, qs = 0.f;
    #pragma unroll
    for (int i = 0; i < 8; ++i) { s += a[i]; qs += a[i]*a[i]; }
    #pragma unroll
    for (int msk = 1; msk < 16; msk <<= 1) {
      s  += __shfl_xor(s,  msk, 64);
      qs += __shfl_xor(qs, msk, 64);
    }
    const float mean = s * (1.f/128.f);
    const float var  = qs * (1.f/128.f) - mean*mean;
    const float rs   = rsqrtf(var + 1e-5f);
    float gg[8], bb[8];
    {
      const float4* gp = (const float4*)(g1  + part*8);
      const float4* ep = (const float4*)(be1 + part*8);
      float4 g0 = gp[0], g1v = gp[1], e0 = ep[0], e1v = ep[1];
      gg[0]=g0.x; gg[1]=g0.y; gg[2]=g0.z; gg[3]=g0.w;
      gg[4]=g1v.x; gg[5]=g1v.y; gg[6]=g1v.z; gg[7]=g1v.w;
      bb[0]=e0.x; bb[1]=e0.y; bb[2]=e0.z; bb[3]=e0.w;
      bb[4]=e1v.x; bb[5]=e1v.y; bb[6]=e1v.z; bb[7]=e1v.w;
    }
    float v[8];
    #pragma unroll
    for (int i = 0; i < 8; ++i)
      v[i] = fmaxf((a[i] - mean)*rs*gg[i] + bb[i], 0.f);
    uint4 pk;
    pk.x = (unsigned)f2bf(v[0]) | ((unsigned)f2bf(v[1]) << 16);
    pk.y = (unsigned)f2bf(v[2]) | ((unsigned)f2bf(v[3]) << 16);
    pk.z = (unsigned)f2bf(v[4]) | ((unsigned)f2bf(v[5]) << 16);
    pk.w = (unsigned)f2bf(v[6]) | ((unsigned)f2bf(v[7]) << 16);
    *(uint4*)&act[tid >> 4][part*8] = pk;
  }
  __syncthreads();

  // ---------------- MFMA phase: 8 waves, wave = nb*2 + rt ----------------
  const int wave = tid >> 6, lane = tid & 63;
  const int l15 = lane & 15, lg = lane >> 4;
  const int rt = wave & 1, nb = wave >> 1;
  const int arow = rt*16 + l15;
  const short8* ws8 = (const short8*)wswz;

  for (int s = 0; s < 3; ++s) {
    f32x4 acc0 = (f32x4){0.f,0.f,0.f,0.f};
    f32x4 acc1 = (f32x4){0.f,0.f,0.f,0.f};
    #pragma unroll
    for (int ks = 0; ks < 4; ++ks) {
      short8 af  = *(const short8*)&act[arow][ks*32 + lg*8];
      short8 bf0 = ws8[s*2048 + ks*512 + (nb*2 + 0)*64 + lane];
      short8 bf1 = ws8[s*2048 + ks*512 + (nb*2 + 1)*64 + lane];
      acc0 = __builtin_amdgcn_mfma_f32_16x16x32_bf16(af, bf0, acc0, 0, 0, 0);
      acc1 = __builtin_amdgcn_mfma_f32_16x16x32_bf16(af, bf1, acc1, 0, 0, 0);
    }
    __syncthreads();   // all act reads done before overwrite

    if (s < 2) {
      const float* bias = (s == 0) ? b2 : pb1;
      const float bb0 = bias[nb*32 + l15], bb1 = bias[nb*32 + 16 + l15];
      #pragma unroll
      for (int q = 0; q < 4; ++q) {
        float x0 = acc0[q] + bb0, x1 = acc1[q] + bb1;
        if (s == 1) { x0 = fmaxf(x0, 0.f); x1 = fmaxf(x1, 0.f); }
        act[rt*16 + lg*4 + q][nb*32 + l15]      = f2bf(x0);
        act[rt*16 + lg*4 + q][nb*32 + 16 + l15] = f2bf(x1);
      }
      __syncthreads();
    } else {
      // ---- final LN: cross-wave row reduction via LDS ----
      const float bb0 = pb2[nb*32 + l15], bb1 = pb2[nb*32 + 16 + l15];
      float w0v[4], w1v[4], sr[4], qr[4];
      #pragma unroll
      for (int q = 0; q < 4; ++q) {
        float x0 = acc0[q] + bb0, x1 = acc1[q] + bb1;
        w0v[q] = x0; w1v[q] = x1;
        sr[q] = x0 + x1; qr[q] = x0*x0 + x1*x1;
      }
      #pragma unroll
      for (int msk = 1; msk < 16; msk <<= 1) {
        #pragma unroll
        for (int q = 0; q < 4; ++q) {
          sr[q] += __shfl_xor(sr[q], msk, 64);
          qr[q] += __shfl_xor(qr[q], msk, 64);
        }
      }
      if (l15 == 0) {
        #pragma unroll
        for (int q = 0; q < 4; ++q) {
          rpart[nb][rt*16 + lg*4 + q][0] = sr[q];
          rpart[nb][rt*16 + lg*4 + q][1] = qr[q];
        }
      }
      __syncthreads();
      if (tid < 64) {
        int row = tid >> 1, vv = tid & 1;
        rfin[row][vv] = rpart[0][row][vv] + rpart[1][row][vv]
                      + rpart[2][row][vv] + rpart[3][row][vv];
      }
      __syncthreads();
      const int c0 = nb*32 + l15, c1 = c0 + 16;
      const float gc0 = ng[c0], gc1 = ng[c1], bc0 = nbv[c0], bc1 = nbv[c1];
      float pc0 = 0.f, pc1 = 0.f;
      #pragma unroll
      for (int q = 0; q < 4; ++q) {
        const int row = rt*16 + lg*4 + q;
        const float mean = rfin[row][0]*(1.f/128.f);
        const float var  = rfin[row][1]*(1.f/128.f) - mean*mean;
        const float rs   = rsqrtf(var + 1e-5f);
        float x0 = (w0v[q] - mean)*rs*gc0 + bc0;
        float x1 = (w1v[q] - mean)*rs*gc1 + bc1;
        act[row][c0] = f2bf(x0);
        act[row][c1] = f2bf(x1);
        pc0 += x0; pc1 += x1;
      }
      pc0 += __shfl_xor(pc0, 16, 64); pc0 += __shfl_xor(pc0, 32, 64);
      pc1 += __shfl_xor(pc1, 16, 64); pc1 += __shfl_xor(pc1, 32, 64);
      if (lg == 0) { gpart[wave][c0] = pc0; gpart[wave][c1] = pc1; }
      __syncthreads();
      if (tid < 128) {
        const int w0 = (tid >> 5)*2;
        float s2 = gpart[w0][tid] + gpart[w0 + 1][tid];
        atomicAdd(&gsum[(blockIdx.x >> 4)*DIM + tid], s2);
      }
      // frag-swizzled xbuf store (rows of this block only)
      {
        short8* xs8 = (short8*)xbuf;
        const int i = tid;                 // 512 = 2 rowgrps * 16 kc * 16 lv
        const int rowgrp = i >> 8, rem = i & 255;
        const int kc = rem >> 4, lv = rem & 15;
        short8 vv = *(const short8*)&act[rowgrp*16 + lv][kc*8];
        xs8[((size_t)(nbase >> 4) + rowgrp)*256 + kc*16 + lv] = vv;
      }
    }
  }
}

// ------- batched X X^T + packed triu write, with exit-MLP tail blocks ------
__global__ __launch_bounds__(256) void k_scores(const unsigned short* __restrict__ xswz,
    const float* __restrict__ gsum,
    const float* __restrict__ eW1, const float* __restrict__ eb1,
    const float* __restrict__ eg,  const float* __restrict__ ebe,
    const float* __restrict__ eW2, const float* __restrict__ eb2,
    float* __restrict__ out)
{
  const int tid = threadIdx.x;

  if (blockIdx.x >= 2560) {
    // exit MLP: 2 graphs per block (128 threads each)
    __shared__ float mrow[2][DIM];
    __shared__ float red[2][2][2];
    __shared__ float red2[2][2];
    const int grp = tid >> 7;
    const int t   = tid & 127;
    const int gi  = ((int)blockIdx.x - 2560)*2 + grp;
    mrow[grp][t] = gsum[gi*DIM + t] * (1.f/512.f);
    __syncthreads();
    float u = eb1[t];
    #pragma unroll 8
    for (int k = 0; k < DIM; ++k) u = fmaf(mrow[grp][k], eW1[k*DIM + t], u);
    float s = u, q = u*u;
    #pragma unroll
    for (int m = 1; m < 64; m <<= 1) { s += __shfl_xor(s, m, 64); q += __shfl_xor(q, m, 64); }
    const int wv = (tid >> 6) & 1;
    if ((tid & 63) == 0) { red[grp][wv][0] = s; red[grp][wv][1] = q; }
    __syncthreads();
    const float S = red[grp][0][0] + red[grp][1][0];
    const float Q = red[grp][0][1] + red[grp][1][1];
    const float mean = S*(1.f/128.f);
    const float var  = Q*(1.f/128.f) - mean*mean;
    float av = fmaxf((u - mean)*rsqrtf(var + 1e-5f)*eg[t] + ebe[t], 0.f);
    float p = av * eW2[t];
    #pragma unroll
    for (int m = 1; m < 64; m <<= 1) p += __shfl_xor(p, m, 64);
    if ((tid & 63) == 0) red2[grp][wv] = p;
    __syncthreads();
    if (t == 0) {
      float e = red2[grp][0] + red2[grp][1] + eb2[0];
      out[gi*3 + 1] = 1.f - e;
      out[gi*3 + 2] = e;
    }
    return;
  }

  static const int TI[10] = {0,0,0,0,1,1,1,2,2,3};
  static const int TJ[10] = {0,1,2,3,1,2,3,2,3,3};
  const int b = blockIdx.x & 255, p = blockIdx.x >> 8;
  const int ti = TI[p], tj = TJ[p];
  const int wave = tid >> 6, lane = tid & 63;
  const int l15 = lane & 15, lg = lane >> 4;
  const short8* Xs = (const short8*)xswz + (size_t)b*8192;  // 512*128/8

  f32x4 acc0[8], acc1[8];
  #pragma unroll
  for (int n = 0; n < 8; ++n) { acc0[n] = (f32x4){0,0,0,0}; acc1[n] = (f32x4){0,0,0,0}; }

  #pragma unroll
  for (int ks = 0; ks < 4; ++ks) {
    const int kq = ks*4 + lg;
    short8 a0 = Xs[(size_t)(ti*8 + wave*2 + 0)*256 + kq*16 + l15];
    short8 a1 = Xs[(size_t)(ti*8 + wave*2 + 1)*256 + kq*16 + l15];
    #pragma unroll
    for (int n = 0; n < 8; ++n) {
      short8 bf = Xs[(size_t)(tj*8 + n)*256 + kq*16 + l15];
      acc0[n] = __builtin_amdgcn_mfma_f32_16x16x32_bf16(a0, bf, acc0[n], 0, 0, 0);
      acc1[n] = __builtin_amdgcn_mfma_f32_16x16x32_bf16(a1, bf, acc1[n], 0, 0, 0);
    }
  }

  const float scale = 0.08838834764831845f;   // 1/sqrt(128)
  float* ea = out + 3072 + (size_t)b*EPB;
  #pragma unroll
  for (int m = 0; m < 2; ++m) {
    #pragma unroll
    for (int n = 0; n < 8; ++n) {
      const int gj = tj*128 + n*16 + l15;
      #pragma unroll
      for (int r = 0; r < 4; ++r) {
        const int gi = ti*128 + wave*32 + m*16 + lg*4 + r;
        if (gi < gj) {
          const int rowbase = gi*511 - (gi*(gi-1))/2 - gi - 1;
          const float v = (m == 0) ? acc0[n][r] : acc1[n][r];
          ea[rowbase + gj] = v * scale;
        }
      }
    }
  }
}

extern "C" void kernel_launch(void* const* d_in, const int* in_sizes, int n_in,
                              void* d_out, int out_size, void* d_ws, size_t ws_size,
                              hipStream_t stream) {
  const int*   nf   = (const int*)d_in[0];
  const int*   ei   = (const int*)d_in[1];
  const float* emb  = (const float*)d_in[3];
  const float* gW1  = (const float*)d_in[4];
  const float* gb1  = (const float*)d_in[5];
  const float* gg1  = (const float*)d_in[6];
  const float* gbe1 = (const float*)d_in[7];
  const float* gW2  = (const float*)d_in[8];
  const float* gb2  = (const float*)d_in[9];
  const float* pW1  = (const float*)d_in[10];
  const float* pb1  = (const float*)d_in[11];
  const float* pW2  = (const float*)d_in[12];
  const float* pb2  = (const float*)d_in[13];
  const float* ng   = (const float*)d_in[14];
  const float* nb   = (const float*)d_in[15];
  const float* eW1  = (const float*)d_in[16];
  const float* eb1  = (const float*)d_in[17];
  const float* eg   = (const float*)d_in[18];
  const float* ebe  = (const float*)d_in[19];
  const float* eW2  = (const float*)d_in[20];
  const float* eb2  = (const float*)d_in[21];
  float* out = (float*)d_out;

  char* ws = (char*)d_ws;
  unsigned short* embW1 = (unsigned short*)ws;                 // 131072 B used
  unsigned short* wswz  = (unsigned short*)(ws + 262144);      // 98304 B
  int*            cnt   = (int*)(ws + 360448);                 // 524288 B
  unsigned short* slots = (unsigned short*)(ws + 884736);      // 8388608 B (CAP=32)
  unsigned short* xbuf  = (unsigned short*)(ws + 13467648);    // 33554432 B
  float*          gsum  = (float*)(ws + 47022080);             // 131072 B
  if (ws_size < 47153152) return;

  k_prep  <<<1100, 256, 0, stream>>>(emb, gW1, embW1, gW2, pW1, pW2, wswz,
                                     cnt, gsum, out);
  k_edges <<<2048, 256, 0, stream>>>(ei, nf, cnt, slots);
  k_gnn   <<<4096, 512, 0, stream>>>(embW1, nf, cnt, slots, gb1, gg1, gbe1,
                                     wswz, gb2, pb1, pb2, ng, nb, xbuf, gsum);
  k_scores<<<2688, 256, 0, stream>>>(xbuf, gsum, eW1, eb1, eg, ebe, eW2, eb2, out);
}

// Round 8
// 150.347 us; speedup vs baseline: 2.4148x; 1.0966x over previous
//
#include <hip/hip_runtime.h>
#include <hip/hip_bf16.h>

#define NBATCH 256
#define NNODES 512
#define DIM    128
#define NTOT   (NBATCH*NNODES)   // 131072
#define NEDGE  (NTOT*8)          // 1048576
#define EPB    130816            // NNODES*(NNODES-1)/2
#define CAP    32

typedef __attribute__((ext_vector_type(8))) short  short8;
typedef __attribute__((ext_vector_type(4))) float  f32x4;

__device__ __forceinline__ unsigned short f2bf(float f){
  unsigned u = __builtin_bit_cast(unsigned, f);
  unsigned r = u + 0x7FFFu + ((u >> 16) & 1u);   // RNE
  return (unsigned short)(r >> 16);
}

// ---- fused prep: embW1 GEMM (bf16 out) + weight frag-swizzle + cnt zero ----
__global__ __launch_bounds__(256) void k_prep(
    const float* __restrict__ emb, const float* __restrict__ W1,
    unsigned short* __restrict__ embW1,
    const float* __restrict__ W2, const float* __restrict__ P1,
    const float* __restrict__ P2, unsigned short* __restrict__ wswz,
    int* __restrict__ cnt)
{
  const int tid = threadIdx.x;
  const int blk = blockIdx.x;
  __shared__ float er[2][DIM];
  if (blk < 256) {
    const int half = tid >> 7, c = tid & 127;
    const int r = blk*2 + half;
    er[half][c] = emb[r*DIM + c];
    __syncthreads();
    float acc = 0.f;
    #pragma unroll 8
    for (int k = 0; k < DIM; ++k) acc = fmaf(er[half][k], W1[k*DIM + c], acc);
    embW1[r*DIM + c] = f2bf(acc);
  } else if (blk < 448) {
    int idx = (blk - 256)*256 + tid;               // 49152 total
    int s = idx >> 14, rem = idx & 16383;
    int ks = rem >> 12, n = (rem >> 9) & 7, lane = (rem >> 3) & 63, j = rem & 7;
    int lg = lane >> 4, l15 = lane & 15;
    int k = ks*32 + lg*8 + j, c = n*16 + l15;
    const float* src = (s == 0) ? W2 : ((s == 1) ? P1 : P2);
    wswz[idx] = f2bf(src[k*DIM + c]);
  } else {
    cnt[(blk - 448)*256 + tid] = 0;                // 512 blocks -> 131072
  }
}

// ------- edge scatter, dst-range partitioned (XCD-local atomics/stores) ----
__global__ __launch_bounds__(256) void k_edges(const int* __restrict__ ei,
                                               const int* __restrict__ nf,
                                               int* __restrict__ cnt,
                                               unsigned short* __restrict__ slots){
  const int base = (blockIdx.x >> 3)*4096 + threadIdx.x;
  const int r    = blockIdx.x & 7;
  #pragma unroll
  for (int it = 0; it < 16; ++it) {
    const int e = base + it*256;
    const int d = ei[NEDGE + e];
    if ((d >> 14) == r) {
      const int s = ei[e];
      const int v = nf[s];
      const int pos = atomicAdd(&cnt[d], 1);
      if (pos < CAP) slots[(size_t)d*CAP + pos] = (unsigned short)v;
    }
  }
}

// ---- mega kernel: one block per batch. gather -> MLP -> LN -> exit -> XX^T
__global__ __launch_bounds__(512, 2) void k_mega(
    const unsigned short* __restrict__ embW1, const int* __restrict__ nf,
    const int* __restrict__ cnt, const unsigned short* __restrict__ slots,
    const float* __restrict__ b1, const float* __restrict__ g1,
    const float* __restrict__ be1,
    const unsigned short* __restrict__ wswz,   // [3][4ks][8n][64lane][8j]
    const float* __restrict__ b2,  const float* __restrict__ pb1, const float* __restrict__ pb2,
    const float* __restrict__ ng,  const float* __restrict__ nbv,
    const float* __restrict__ eW1, const float* __restrict__ eb1,
    const float* __restrict__ eg,  const float* __restrict__ ebe,
    const float* __restrict__ eW2, const float* __restrict__ eb2,
    float* __restrict__ out)
{
  __shared__ unsigned short X[512][136];   // 139264 B; stride 272B: 16B-aligned, bank-balanced
  __shared__ float gpart[8][128];
  __shared__ float mrow[128];
  __shared__ float redA[4];
  __shared__ float redB[2];
  const int tid   = threadIdx.x;
  const int bb    = blockIdx.x;            // batch index
  const int nbase = bb * NNODES;

  // ---------------- gather phase: 16 passes x 32 nodes ----------------
  {
    const int part = tid & 15;
    const short8* base8 = (const short8*)embW1;
    #pragma unroll 1
    for (int pass = 0; pass < 16; ++pass) {
      const int lnode = pass*32 + (tid >> 4);
      const int node  = nbase + lnode;
      const int self = nf[node];
      int m = cnt[node]; if (m > CAP) m = CAP;
      const unsigned short* sl = slots + (size_t)node*CAP;
      const uint4 sv0 = *(const uint4*)(sl);
      const uint4 sv1 = *(const uint4*)(sl + 8);
      const uint4 sv2 = *(const uint4*)(sl + 16);
      unsigned sw[12] = {sv0.x,sv0.y,sv0.z,sv0.w, sv1.x,sv1.y,sv1.z,sv1.w,
                         sv2.x,sv2.y,sv2.z,sv2.w};
      float a[8];
      {
        const float4* bp = (const float4*)(b1 + part*8);
        float4 x = bp[0], y = bp[1];
        a[0]=x.x; a[1]=x.y; a[2]=x.z; a[3]=x.w;
        a[4]=y.x; a[5]=y.y; a[6]=y.z; a[7]=y.w;
      }
#define ACC8(V) { _Pragma("unroll") \
      for (int i_ = 0; i_ < 8; ++i_) { \
        unsigned uu = ((unsigned)(unsigned short)(V)[i_]) << 16; \
        a[i_] += __builtin_bit_cast(float, uu); } }
      {
        short8 t0 = base8[(size_t)self*16 + part];
        short8 t[8];
        #pragma unroll
        for (int e = 0; e < 8; ++e) {
          unsigned id = (sw[e >> 1] >> ((e & 1)*16)) & 0xffffu;
          int idx = (e < m) ? (int)id : self;
          t[e] = base8[(size_t)idx*16 + part];
        }
        ACC8(t0)
        #pragma unroll
        for (int e = 0; e < 8; ++e) if (e < m) ACC8(t[e])
      }
      if (m > 8) {
        short8 t[8];
        #pragma unroll
        for (int e = 0; e < 8; ++e) {
          unsigned id = (sw[4 + (e >> 1)] >> ((e & 1)*16)) & 0xffffu;
          int idx = (e + 8 < m) ? (int)id : self;
          t[e] = base8[(size_t)idx*16 + part];
        }
        #pragma unroll
        for (int e = 0; e < 8; ++e) if (e + 8 < m) ACC8(t[e])
      }
      if (m > 16) {
        short8 t[8];
        #pragma unroll
        for (int e = 0; e < 8; ++e) {
          unsigned id = (sw[8 + (e >> 1)] >> ((e & 1)*16)) & 0xffffu;
          int idx = (e + 16 < m) ? (int)id : self;
          t[e] = base8[(size_t)idx*16 + part];
        }
        #pragma unroll
        for (int e = 0; e < 8; ++e) if (e + 16 < m) ACC8(t[e])
      }
      for (int e = 24; e < m; ++e) {
        short8 t = base8[(size_t)sl[e]*16 + part];
        ACC8(t)
      }
      float s = 0.f, qs = 0.f;
      #pragma unroll
      for (int i = 0; i < 8; ++i) { s += a[i]; qs += a[i]*a[i]; }
      #pragma unroll
      for (int msk = 1; msk < 16; msk <<= 1) {
        s  += __shfl_xor(s,  msk, 64);
        qs += __shfl_xor(qs, msk, 64);
      }
      const float mean = s * (1.f/128.f);
      const float var  = qs * (1.f/128.f) - mean*mean;
      const float rs   = rsqrtf(var + 1e-5f);
      const float4* gp = (const float4*)(g1  + part*8);
      const float4* ep = (const float4*)(be1 + part*8);
      float4 g0 = gp[0], g1v = gp[1], e0 = ep[0], e1v = ep[1];
      float gg[8] = {g0.x,g0.y,g0.z,g0.w, g1v.x,g1v.y,g1v.z,g1v.w};
      float eb[8] = {e0.x,e0.y,e0.z,e0.w, e1v.x,e1v.y,e1v.z,e1v.w};
      float v[8];
      #pragma unroll
      for (int i = 0; i < 8; ++i)
        v[i] = fmaxf((a[i] - mean)*rs*gg[i] + eb[i], 0.f);
      uint4 pk;
      pk.x = (unsigned)f2bf(v[0]) | ((unsigned)f2bf(v[1]) << 16);
      pk.y = (unsigned)f2bf(v[2]) | ((unsigned)f2bf(v[3]) << 16);
      pk.z = (unsigned)f2bf(v[4]) | ((unsigned)f2bf(v[5]) << 16);
      pk.w = (unsigned)f2bf(v[6]) | ((unsigned)f2bf(v[7]) << 16);
      *(uint4*)&X[lnode][part*8] = pk;
    }
  }
  __syncthreads();

  // ---------------- MLP phase: wave-private rows, no barriers ----------------
  const int wave = tid >> 6, lane = tid & 63;
  const int l15 = lane & 15, lg = lane >> 4;
  const short8* ws8 = (const short8*)wswz;
  float pc[8];
  #pragma unroll
  for (int n = 0; n < 8; ++n) pc[n] = 0.f;

  #pragma unroll
  for (int s = 0; s < 3; ++s) {
    f32x4 acc[4][8];
    #pragma unroll
    for (int p4 = 0; p4 < 4; ++p4)
      #pragma unroll
      for (int n = 0; n < 8; ++n) acc[p4][n] = (f32x4){0.f,0.f,0.f,0.f};
    #pragma unroll
    for (int ks = 0; ks < 4; ++ks) {
      short8 bf[8];
      #pragma unroll
      for (int n = 0; n < 8; ++n) bf[n] = ws8[s*2048 + ks*512 + n*64 + lane];
      #pragma unroll
      for (int p4 = 0; p4 < 4; ++p4) {
        short8 af = *(const short8*)&X[p4*128 + wave*16 + l15][ks*32 + lg*8];
        #pragma unroll
        for (int n = 0; n < 8; ++n)
          acc[p4][n] = __builtin_amdgcn_mfma_f32_16x16x32_bf16(af, bf[n], acc[p4][n], 0, 0, 0);
      }
    }
    if (s < 2) {
      const float* bias = (s == 0) ? b2 : pb1;
      float bv[8];
      #pragma unroll
      for (int n = 0; n < 8; ++n) bv[n] = bias[n*16 + l15];
      #pragma unroll
      for (int p4 = 0; p4 < 4; ++p4)
        #pragma unroll
        for (int n = 0; n < 8; ++n)
          #pragma unroll
          for (int q = 0; q < 4; ++q) {
            float v = acc[p4][n][q] + bv[n];
            if (s == 1) v = fmaxf(v, 0.f);
            X[p4*128 + wave*16 + lg*4 + q][n*16 + l15] = f2bf(v);
          }
      // same-wave LDS RAW: ds ops process in order; no barrier needed
    } else {
      float bv[8], gc[8], bc[8];
      #pragma unroll
      for (int n = 0; n < 8; ++n) {
        bv[n] = pb2[n*16 + l15];
        gc[n] = ng [n*16 + l15];
        bc[n] = nbv[n*16 + l15];
      }
      #pragma unroll
      for (int p4 = 0; p4 < 4; ++p4) {
        float sr[4] = {0,0,0,0}, qr[4] = {0,0,0,0};
        #pragma unroll
        for (int n = 0; n < 8; ++n)
          #pragma unroll
          for (int q = 0; q < 4; ++q) {
            float v = acc[p4][n][q] + bv[n];
            acc[p4][n][q] = v;
            sr[q] += v; qr[q] += v*v;
          }
        #pragma unroll
        for (int msk = 1; msk < 16; msk <<= 1)
          #pragma unroll
          for (int q = 0; q < 4; ++q) {
            sr[q] += __shfl_xor(sr[q], msk, 64);
            qr[q] += __shfl_xor(qr[q], msk, 64);
          }
        float mean[4], rs[4];
        #pragma unroll
        for (int q = 0; q < 4; ++q) {
          mean[q] = sr[q]*(1.f/128.f);
          float var = qr[q]*(1.f/128.f) - mean[q]*mean[q];
          rs[q] = rsqrtf(var + 1e-5f);
        }
        #pragma unroll
        for (int n = 0; n < 8; ++n)
          #pragma unroll
          for (int q = 0; q < 4; ++q) {
            float xo = (acc[p4][n][q] - mean[q])*rs[q]*gc[n] + bc[n];
            X[p4*128 + wave*16 + lg*4 + q][n*16 + l15] = f2bf(xo);
            pc[n] += xo;
          }
      }
    }
  }
  // column partials: reduce over lg, store per wave
  #pragma unroll
  for (int n = 0; n < 8; ++n) {
    pc[n] += __shfl_xor(pc[n], 16, 64);
    pc[n] += __shfl_xor(pc[n], 32, 64);
  }
  if (lg == 0) {
    #pragma unroll
    for (int n = 0; n < 8; ++n) gpart[wave][n*16 + l15] = pc[n];
  }
  __syncthreads();

  // ---------------- exit MLP (in-block; waves 0-1) ----------------
  if (tid < 128) {
    float m = 0.f;
    #pragma unroll
    for (int w = 0; w < 8; ++w) m += gpart[w][tid];
    mrow[tid] = m * (1.f/512.f);
  }
  __syncthreads();
  float uu = 0.f;
  if (tid < 128) {
    uu = eb1[tid];
    #pragma unroll 8
    for (int k = 0; k < DIM; ++k) uu = fmaf(mrow[k], eW1[k*DIM + tid], uu);
    float s2 = uu, q2 = uu*uu;
    #pragma unroll
    for (int msk = 1; msk < 64; msk <<= 1) {
      s2 += __shfl_xor(s2, msk, 64); q2 += __shfl_xor(q2, msk, 64);
    }
    if ((tid & 63) == 0) { redA[(tid >> 6)*2] = s2; redA[(tid >> 6)*2 + 1] = q2; }
  }
  __syncthreads();
  if (tid < 128) {
    const float S = redA[0] + redA[2], Q = redA[1] + redA[3];
    const float mean = S*(1.f/128.f);
    const float var  = Q*(1.f/128.f) - mean*mean;
    float av = fmaxf((uu - mean)*rsqrtf(var + 1e-5f)*eg[tid] + ebe[tid], 0.f);
    float p = av * eW2[tid];
    #pragma unroll
    for (int msk = 1; msk < 64; msk <<= 1) p += __shfl_xor(p, msk, 64);
    if ((tid & 63) == 0) redB[tid >> 6] = p;
  }
  __syncthreads();
  if (tid == 0) {
    float e = redB[0] + redB[1] + eb2[0];
    out[bb*3 + 0] = 0.f;
    out[bb*3 + 1] = 1.f - e;
    out[bb*3 + 2] = e;
  }
  if (tid < 8)   out[768 + bb*8 + tid] = 0.f;   // edge_class
  if (tid == 8)  out[2816 + bb] = 0.f;          // node_class

  // ---------------- scores phase: X X^T from LDS, packed triu ----------------
  float* ea = out + 3072 + (size_t)bb*EPB;
  const float scale = 0.08838834764831845f;     // 1/sqrt(128)
  #pragma unroll 1
  for (int i = 0; i < 5; ++i) {
    const int task = wave*5 + i;                // 40 tasks = 10 tiles x 4 rowgrps
    const int p  = task >> 2, rg = task & 3;
    const int ti = (int)((0x3221110000ULL >> (p*4)) & 0xF);
    const int tj = (int)((0x3323213210ULL >> (p*4)) & 0xF);
    f32x4 acc0[8], acc1[8];
    #pragma unroll
    for (int n = 0; n < 8; ++n) { acc0[n] = (f32x4){0,0,0,0}; acc1[n] = (f32x4){0,0,0,0}; }
    #pragma unroll
    for (int ks = 0; ks < 4; ++ks) {
      const int k0 = ks*32 + lg*8;
      short8 a0 = *(const short8*)&X[ti*128 + rg*32 +      l15][k0];
      short8 a1 = *(const short8*)&X[ti*128 + rg*32 + 16 + l15][k0];
      #pragma unroll
      for (int n = 0; n < 8; ++n) {
        short8 bf = *(const short8*)&X[tj*128 + n*16 + l15][k0];
        acc0[n] = __builtin_amdgcn_mfma_f32_16x16x32_bf16(a0, bf, acc0[n], 0, 0, 0);
        acc1[n] = __builtin_amdgcn_mfma_f32_16x16x32_bf16(a1, bf, acc1[n], 0, 0, 0);
      }
    }
    #pragma unroll
    for (int m = 0; m < 2; ++m) {
      #pragma unroll
      for (int n = 0; n < 8; ++n) {
        const int gj = tj*128 + n*16 + l15;
        #pragma unroll
        for (int r = 0; r < 4; ++r) {
          const int gi = ti*128 + rg*32 + m*16 + lg*4 + r;
          if (gi < gj) {
            const int rowbase = gi*511 - (gi*(gi-1))/2 - gi - 1;
            const float v = (m == 0) ? acc0[n][r] : acc1[n][r];
            ea[rowbase + gj] = v * scale;
          }
        }
      }
    }
  }
}

extern "C" void kernel_launch(void* const* d_in, const int* in_sizes, int n_in,
                              void* d_out, int out_size, void* d_ws, size_t ws_size,
                              hipStream_t stream) {
  const int*   nf   = (const int*)d_in[0];
  const int*   ei   = (const int*)d_in[1];
  const float* emb  = (const float*)d_in[3];
  const float* gW1  = (const float*)d_in[4];
  const float* gb1  = (const float*)d_in[5];
  const float* gg1  = (const float*)d_in[6];
  const float* gbe1 = (const float*)d_in[7];
  const float* gW2  = (const float*)d_in[8];
  const float* gb2  = (const float*)d_in[9];
  const float* pW1  = (const float*)d_in[10];
  const float* pb1  = (const float*)d_in[11];
  const float* pW2  = (const float*)d_in[12];
  const float* pb2  = (const float*)d_in[13];
  const float* ng   = (const float*)d_in[14];
  const float* nb   = (const float*)d_in[15];
  const float* eW1  = (const float*)d_in[16];
  const float* eb1  = (const float*)d_in[17];
  const float* eg   = (const float*)d_in[18];
  const float* ebe  = (const float*)d_in[19];
  const float* eW2  = (const float*)d_in[20];
  const float* eb2  = (const float*)d_in[21];
  float* out = (float*)d_out;

  char* ws = (char*)d_ws;
  unsigned short* embW1 = (unsigned short*)ws;                 // 131072 B used
  unsigned short* wswz  = (unsigned short*)(ws + 262144);      // 98304 B
  int*            cnt   = (int*)(ws + 360448);                 // 524288 B
  unsigned short* slots = (unsigned short*)(ws + 884736);      // 8388608 B (CAP=32)
  if (ws_size < 9273344) return;

  k_prep  <<<960,  256, 0, stream>>>(emb, gW1, embW1, gW2, pW1, pW2, wswz, cnt);
  k_edges <<<2048, 256, 0, stream>>>(ei, nf, cnt, slots);
  k_mega  <<<256,  512, 0, stream>>>(embW1, nf, cnt, slots, gb1, gg1, gbe1,
                                     wswz, gb2, pb1, pb2, ng, nb,
                                     eW1, eb1, eg, ebe, eW2, eb2, out);
}

// Round 9
// 146.226 us; speedup vs baseline: 2.4828x; 1.0282x over previous
//
#include <hip/hip_runtime.h>
#include <hip/hip_bf16.h>

#define NBATCH 256
#define NNODES 512
#define DIM    128
#define NTOT   (NBATCH*NNODES)   // 131072
#define NEDGE  (NTOT*8)          // 1048576
#define EPB    130816            // NNODES*(NNODES-1)/2
#define CAP    32

typedef __attribute__((ext_vector_type(8))) short  short8;
typedef __attribute__((ext_vector_type(4))) float  f32x4;

__device__ __forceinline__ unsigned short f2bf(float f){
  unsigned u = __builtin_bit_cast(unsigned, f);
  unsigned r = u + 0x7FFFu + ((u >> 16) & 1u);   // RNE
  return (unsigned short)(r >> 16);
}

// ---- fused prep: embW1 GEMM (bf16 out) + weight frag-swizzle + cnt zero ----
__global__ __launch_bounds__(256) void k_prep(
    const float* __restrict__ emb, const float* __restrict__ W1,
    unsigned short* __restrict__ embW1,
    const float* __restrict__ W2, const float* __restrict__ P1,
    const float* __restrict__ P2, unsigned short* __restrict__ wswz,
    int* __restrict__ cnt)
{
  const int tid = threadIdx.x;
  const int blk = blockIdx.x;
  __shared__ float er[2][DIM];
  if (blk < 256) {
    const int half = tid >> 7, c = tid & 127;
    const int r = blk*2 + half;
    er[half][c] = emb[r*DIM + c];
    __syncthreads();
    float acc = 0.f;
    #pragma unroll 8
    for (int k = 0; k < DIM; ++k) acc = fmaf(er[half][k], W1[k*DIM + c], acc);
    embW1[r*DIM + c] = f2bf(acc);
  } else if (blk < 448) {
    int idx = (blk - 256)*256 + tid;               // 49152 total
    int s = idx >> 14, rem = idx & 16383;
    int ks = rem >> 12, n = (rem >> 9) & 7, lane = (rem >> 3) & 63, j = rem & 7;
    int lg = lane >> 4, l15 = lane & 15;
    int k = ks*32 + lg*8 + j, c = n*16 + l15;
    const float* src = (s == 0) ? W2 : ((s == 1) ? P1 : P2);
    wswz[idx] = f2bf(src[k*DIM + c]);
  } else {
    cnt[(blk - 448)*256 + tid] = 0;                // 512 blocks -> 131072
  }
}

// ------- edge scatter, dst-range partitioned (XCD-local atomics/stores) ----
__global__ __launch_bounds__(256) void k_edges(const int* __restrict__ ei,
                                               const int* __restrict__ nf,
                                               int* __restrict__ cnt,
                                               unsigned short* __restrict__ slots){
  const int base = (blockIdx.x >> 3)*4096 + threadIdx.x;
  const int r    = blockIdx.x & 7;
  #pragma unroll
  for (int it = 0; it < 16; ++it) {
    const int e = base + it*256;
    const int d = ei[NEDGE + e];
    if ((d >> 14) == r) {
      const int s = ei[e];
      const int v = nf[s];
      const int pos = atomicAdd(&cnt[d], 1);
      if (pos < CAP) slots[(size_t)d*CAP + pos] = (unsigned short)v;
    }
  }
}

// ---- mega kernel: one block per batch, 1024 threads (16 waves/CU).
//      gather -> MLP -> LN -> exit -> XX^T, X resident in LDS throughout.
__global__ __launch_bounds__(1024, 1) void k_mega(
    const unsigned short* __restrict__ embW1, const int* __restrict__ nf,
    const int* __restrict__ cnt, const unsigned short* __restrict__ slots,
    const float* __restrict__ b1, const float* __restrict__ g1,
    const float* __restrict__ be1,
    const unsigned short* __restrict__ wswz,   // [3][4ks][8n][64lane][8j]
    const float* __restrict__ b2,  const float* __restrict__ pb1, const float* __restrict__ pb2,
    const float* __restrict__ ng,  const float* __restrict__ nbv,
    const float* __restrict__ eW1, const float* __restrict__ eb1,
    const float* __restrict__ eg,  const float* __restrict__ ebe,
    const float* __restrict__ eW2, const float* __restrict__ eb2,
    float* __restrict__ out)
{
  __shared__ unsigned short X[512][136];   // 139264 B
  __shared__ float gpart[16][128];
  __shared__ float mrow[128];
  __shared__ float redA[4];
  __shared__ float redB[2];
  const int tid   = threadIdx.x;
  const int bb    = blockIdx.x;            // batch index
  const int nbase = bb * NNODES;

  // ---------------- gather phase: 8 passes x 64 nodes ----------------
  {
    const int part = tid & 15;
    const short8* base8 = (const short8*)embW1;
    #pragma unroll 1
    for (int pass = 0; pass < 8; ++pass) {
      const int lnode = pass*64 + (tid >> 4);
      const int node  = nbase + lnode;
      const int self = nf[node];
      int m = cnt[node]; if (m > CAP) m = CAP;
      const unsigned short* sl = slots + (size_t)node*CAP;
      const uint4 sv0 = *(const uint4*)(sl);
      const uint4 sv1 = *(const uint4*)(sl + 8);
      const uint4 sv2 = *(const uint4*)(sl + 16);
      unsigned sw[12] = {sv0.x,sv0.y,sv0.z,sv0.w, sv1.x,sv1.y,sv1.z,sv1.w,
                         sv2.x,sv2.y,sv2.z,sv2.w};
      float a[8];
      {
        const float4* bp = (const float4*)(b1 + part*8);
        float4 x = bp[0], y = bp[1];
        a[0]=x.x; a[1]=x.y; a[2]=x.z; a[3]=x.w;
        a[4]=y.x; a[5]=y.y; a[6]=y.z; a[7]=y.w;
      }
#define ACC8(V) { _Pragma("unroll") \
      for (int i_ = 0; i_ < 8; ++i_) { \
        unsigned uu = ((unsigned)(unsigned short)(V)[i_]) << 16; \
        a[i_] += __builtin_bit_cast(float, uu); } }
      {
        short8 t0 = base8[(size_t)self*16 + part];
        short8 t[8];
        #pragma unroll
        for (int e = 0; e < 8; ++e) {
          unsigned id = (sw[e >> 1] >> ((e & 1)*16)) & 0xffffu;
          int idx = (e < m) ? (int)id : self;
          t[e] = base8[(size_t)idx*16 + part];
        }
        ACC8(t0)
        #pragma unroll
        for (int e = 0; e < 8; ++e) if (e < m) ACC8(t[e])
      }
      if (m > 8) {
        short8 t[8];
        #pragma unroll
        for (int e = 0; e < 8; ++e) {
          unsigned id = (sw[4 + (e >> 1)] >> ((e & 1)*16)) & 0xffffu;
          int idx = (e + 8 < m) ? (int)id : self;
          t[e] = base8[(size_t)idx*16 + part];
        }
        #pragma unroll
        for (int e = 0; e < 8; ++e) if (e + 8 < m) ACC8(t[e])
      }
      if (m > 16) {
        short8 t[8];
        #pragma unroll
        for (int e = 0; e < 8; ++e) {
          unsigned id = (sw[8 + (e >> 1)] >> ((e & 1)*16)) & 0xffffu;
          int idx = (e + 16 < m) ? (int)id : self;
          t[e] = base8[(size_t)idx*16 + part];
        }
        #pragma unroll
        for (int e = 0; e < 8; ++e) if (e + 16 < m) ACC8(t[e])
      }
      for (int e = 24; e < m; ++e) {
        short8 t = base8[(size_t)sl[e]*16 + part];
        ACC8(t)
      }
      float s = 0.f, qs = 0.f;
      #pragma unroll
      for (int i = 0; i < 8; ++i) { s += a[i]; qs += a[i]*a[i]; }
      #pragma unroll
      for (int msk = 1; msk < 16; msk <<= 1) {
        s  += __shfl_xor(s,  msk, 64);
        qs += __shfl_xor(qs, msk, 64);
      }
      const float mean = s * (1.f/128.f);
      const float var  = qs * (1.f/128.f) - mean*mean;
      const float rs   = rsqrtf(var + 1e-5f);
      const float4* gp = (const float4*)(g1  + part*8);
      const float4* ep = (const float4*)(be1 + part*8);
      float4 g0 = gp[0], g1v = gp[1], e0 = ep[0], e1v = ep[1];
      float gg[8] = {g0.x,g0.y,g0.z,g0.w, g1v.x,g1v.y,g1v.z,g1v.w};
      float eb[8] = {e0.x,e0.y,e0.z,e0.w, e1v.x,e1v.y,e1v.z,e1v.w};
      float v[8];
      #pragma unroll
      for (int i = 0; i < 8; ++i)
        v[i] = fmaxf((a[i] - mean)*rs*gg[i] + eb[i], 0.f);
      uint4 pk;
      pk.x = (unsigned)f2bf(v[0]) | ((unsigned)f2bf(v[1]) << 16);
      pk.y = (unsigned)f2bf(v[2]) | ((unsigned)f2bf(v[3]) << 16);
      pk.z = (unsigned)f2bf(v[4]) | ((unsigned)f2bf(v[5]) << 16);
      pk.w = (unsigned)f2bf(v[6]) | ((unsigned)f2bf(v[7]) << 16);
      *(uint4*)&X[lnode][part*8] = pk;
    }
  }
  __syncthreads();

  // ------------- MLP phase: 16 waves, wave-private rows, no barriers -------
  const int wave = tid >> 6, lane = tid & 63;
  const int l15 = lane & 15, lg = lane >> 4;
  const short8* ws8 = (const short8*)wswz;
  float pc[8];
  #pragma unroll
  for (int n = 0; n < 8; ++n) pc[n] = 0.f;

  #pragma unroll
  for (int s = 0; s < 3; ++s) {
    f32x4 acc[2][8];
    #pragma unroll
    for (int p2 = 0; p2 < 2; ++p2)
      #pragma unroll
      for (int n = 0; n < 8; ++n) acc[p2][n] = (f32x4){0.f,0.f,0.f,0.f};
    #pragma unroll
    for (int ks = 0; ks < 4; ++ks) {
      short8 bf[8];
      #pragma unroll
      for (int n = 0; n < 8; ++n) bf[n] = ws8[s*2048 + ks*512 + n*64 + lane];
      #pragma unroll
      for (int p2 = 0; p2 < 2; ++p2) {
        short8 af = *(const short8*)&X[p2*256 + wave*16 + l15][ks*32 + lg*8];
        #pragma unroll
        for (int n = 0; n < 8; ++n)
          acc[p2][n] = __builtin_amdgcn_mfma_f32_16x16x32_bf16(af, bf[n], acc[p2][n], 0, 0, 0);
      }
    }
    if (s < 2) {
      const float* bias = (s == 0) ? b2 : pb1;
      float bv[8];
      #pragma unroll
      for (int n = 0; n < 8; ++n) bv[n] = bias[n*16 + l15];
      #pragma unroll
      for (int p2 = 0; p2 < 2; ++p2)
        #pragma unroll
        for (int n = 0; n < 8; ++n)
          #pragma unroll
          for (int q = 0; q < 4; ++q) {
            float v = acc[p2][n][q] + bv[n];
            if (s == 1) v = fmaxf(v, 0.f);
            X[p2*256 + wave*16 + lg*4 + q][n*16 + l15] = f2bf(v);
          }
      // same-wave LDS RAW: in-order ds pipeline; no barrier needed
    } else {
      float bv[8], gc[8], bc[8];
      #pragma unroll
      for (int n = 0; n < 8; ++n) {
        bv[n] = pb2[n*16 + l15];
        gc[n] = ng [n*16 + l15];
        bc[n] = nbv[n*16 + l15];
      }
      #pragma unroll
      for (int p2 = 0; p2 < 2; ++p2) {
        float sr[4] = {0,0,0,0}, qr[4] = {0,0,0,0};
        #pragma unroll
        for (int n = 0; n < 8; ++n)
          #pragma unroll
          for (int q = 0; q < 4; ++q) {
            float v = acc[p2][n][q] + bv[n];
            acc[p2][n][q] = v;
            sr[q] += v; qr[q] += v*v;
          }
        #pragma unroll
        for (int msk = 1; msk < 16; msk <<= 1)
          #pragma unroll
          for (int q = 0; q < 4; ++q) {
            sr[q] += __shfl_xor(sr[q], msk, 64);
            qr[q] += __shfl_xor(qr[q], msk, 64);
          }
        float mean[4], rs[4];
        #pragma unroll
        for (int q = 0; q < 4; ++q) {
          mean[q] = sr[q]*(1.f/128.f);
          float var = qr[q]*(1.f/128.f) - mean[q]*mean[q];
          rs[q] = rsqrtf(var + 1e-5f);
        }
        #pragma unroll
        for (int n = 0; n < 8; ++n)
          #pragma unroll
          for (int q = 0; q < 4; ++q) {
            float xo = (acc[p2][n][q] - mean[q])*rs[q]*gc[n] + bc[n];
            X[p2*256 + wave*16 + lg*4 + q][n*16 + l15] = f2bf(xo);
            pc[n] += xo;
          }
      }
    }
  }
  // column partials: reduce over lg, store per wave
  #pragma unroll
  for (int n = 0; n < 8; ++n) {
    pc[n] += __shfl_xor(pc[n], 16, 64);
    pc[n] += __shfl_xor(pc[n], 32, 64);
  }
  if (lg == 0) {
    #pragma unroll
    for (int n = 0; n < 8; ++n) gpart[wave][n*16 + l15] = pc[n];
  }
  __syncthreads();

  // ---------------- exit MLP (in-block; waves 0-1) ----------------
  if (tid < 128) {
    float m = 0.f;
    #pragma unroll
    for (int w = 0; w < 16; ++w) m += gpart[w][tid];
    mrow[tid] = m * (1.f/512.f);
  }
  __syncthreads();
  float uu = 0.f;
  if (tid < 128) {
    uu = eb1[tid];
    #pragma unroll 8
    for (int k = 0; k < DIM; ++k) uu = fmaf(mrow[k], eW1[k*DIM + tid], uu);
    float s2 = uu, q2 = uu*uu;
    #pragma unroll
    for (int msk = 1; msk < 64; msk <<= 1) {
      s2 += __shfl_xor(s2, msk, 64); q2 += __shfl_xor(q2, msk, 64);
    }
    if ((tid & 63) == 0) { redA[(tid >> 6)*2] = s2; redA[(tid >> 6)*2 + 1] = q2; }
  }
  __syncthreads();
  if (tid < 128) {
    const float S = redA[0] + redA[2], Q = redA[1] + redA[3];
    const float mean = S*(1.f/128.f);
    const float var  = Q*(1.f/128.f) - mean*mean;
    float av = fmaxf((uu - mean)*rsqrtf(var + 1e-5f)*eg[tid] + ebe[tid], 0.f);
    float p = av * eW2[tid];
    #pragma unroll
    for (int msk = 1; msk < 64; msk <<= 1) p += __shfl_xor(p, msk, 64);
    if ((tid & 63) == 0) redB[tid >> 6] = p;
  }
  __syncthreads();
  if (tid == 0) {
    float e = redB[0] + redB[1] + eb2[0];
    out[bb*3 + 0] = 0.f;
    out[bb*3 + 1] = 1.f - e;
    out[bb*3 + 2] = e;
  }
  if (tid < 8)   out[768 + bb*8 + tid] = 0.f;   // edge_class
  if (tid == 8)  out[2816 + bb] = 0.f;          // node_class

  // ------------- scores phase: 80 tasks (10 tiles x 8 rowgrps), 5/wave ------
  float* ea = out + 3072 + (size_t)bb*EPB;
  const float scale = 0.08838834764831845f;     // 1/sqrt(128)
  #pragma unroll 1
  for (int i = 0; i < 5; ++i) {
    const int task = wave*5 + i;                // 0..79
    const int p  = task >> 3, rg = task & 7;
    const int ti = (int)((0x3221110000ULL >> (p*4)) & 0xF);
    const int tj = (int)((0x3323213210ULL >> (p*4)) & 0xF);
    f32x4 acc[8];
    #pragma unroll
    for (int n = 0; n < 8; ++n) acc[n] = (f32x4){0,0,0,0};
    #pragma unroll
    for (int ks = 0; ks < 4; ++ks) {
      const int k0 = ks*32 + lg*8;
      short8 a0 = *(const short8*)&X[ti*128 + rg*16 + l15][k0];
      #pragma unroll
      for (int n = 0; n < 8; ++n) {
        short8 bf = *(const short8*)&X[tj*128 + n*16 + l15][k0];
        acc[n] = __builtin_amdgcn_mfma_f32_16x16x32_bf16(a0, bf, acc[n], 0, 0, 0);
      }
    }
    #pragma unroll
    for (int n = 0; n < 8; ++n) {
      const int gj = tj*128 + n*16 + l15;
      #pragma unroll
      for (int r = 0; r < 4; ++r) {
        const int gi = ti*128 + rg*16 + lg*4 + r;
        if (gi < gj) {
          const int rowbase = gi*511 - (gi*(gi-1))/2 - gi - 1;
          ea[rowbase + gj] = acc[n][r] * scale;
        }
      }
    }
  }
}

extern "C" void kernel_launch(void* const* d_in, const int* in_sizes, int n_in,
                              void* d_out, int out_size, void* d_ws, size_t ws_size,
                              hipStream_t stream) {
  const int*   nf   = (const int*)d_in[0];
  const int*   ei   = (const int*)d_in[1];
  const float* emb  = (const float*)d_in[3];
  const float* gW1  = (const float*)d_in[4];
  const float* gb1  = (const float*)d_in[5];
  const float* gg1  = (const float*)d_in[6];
  const float* gbe1 = (const float*)d_in[7];
  const float* gW2  = (const float*)d_in[8];
  const float* gb2  = (const float*)d_in[9];
  const float* pW1  = (const float*)d_in[10];
  const float* pb1  = (const float*)d_in[11];
  const float* pW2  = (const float*)d_in[12];
  const float* pb2  = (const float*)d_in[13];
  const float* ng   = (const float*)d_in[14];
  const float* nb   = (const float*)d_in[15];
  const float* eW1  = (const float*)d_in[16];
  const float* eb1  = (const float*)d_in[17];
  const float* eg   = (const float*)d_in[18];
  const float* ebe  = (const float*)d_in[19];
  const float* eW2  = (const float*)d_in[20];
  const float* eb2  = (const float*)d_in[21];
  float* out = (float*)d_out;

  char* ws = (char*)d_ws;
  unsigned short* embW1 = (unsigned short*)ws;                 // 131072 B used
  unsigned short* wswz  = (unsigned short*)(ws + 262144);      // 98304 B
  int*            cnt   = (int*)(ws + 360448);                 // 524288 B
  unsigned short* slots = (unsigned short*)(ws + 884736);      // 8388608 B (CAP=32)
  if (ws_size < 9273344) return;

  k_prep  <<<960,  256, 0, stream>>>(emb, gW1, embW1, gW2, pW1, pW2, wswz, cnt);
  k_edges <<<2048, 256, 0, stream>>>(ei, nf, cnt, slots);
  k_mega  <<<256, 1024, 0, stream>>>(embW1, nf, cnt, slots, gb1, gg1, gbe1,
                                     wswz, gb2, pb1, pb2, ng, nb,
                                     eW1, eb1, eg, ebe, eW2, eb2, out);
}

// Round 10
// 138.066 us; speedup vs baseline: 2.6295x; 1.0591x over previous
//
#include <hip/hip_runtime.h>
#include <hip/hip_bf16.h>

#define NBATCH 256
#define NNODES 512
#define DIM    128
#define NTOT   (NBATCH*NNODES)   // 131072
#define NEDGE  (NTOT*8)          // 1048576
#define EPB    130816            // NNODES*(NNODES-1)/2
#define CAP    32

typedef __attribute__((ext_vector_type(8))) short  short8;
typedef __attribute__((ext_vector_type(4))) float  f32x4;

__device__ __forceinline__ unsigned short f2bf(float f){
  unsigned u = __builtin_bit_cast(unsigned, f);
  unsigned r = u + 0x7FFFu + ((u >> 16) & 1u);   // RNE
  return (unsigned short)(r >> 16);
}

// ---- fused prep: embW1 GEMM (bf16 out) + weight frag-swizzle + cnt zero ----
__global__ __launch_bounds__(256) void k_prep(
    const float* __restrict__ emb, const float* __restrict__ W1,
    unsigned short* __restrict__ embW1,
    const float* __restrict__ W2, const float* __restrict__ P1,
    const float* __restrict__ P2, unsigned short* __restrict__ wswz,
    int* __restrict__ cnt)
{
  const int tid = threadIdx.x;
  const int blk = blockIdx.x;
  __shared__ float er[2][DIM];
  if (blk < 256) {
    const int half = tid >> 7, c = tid & 127;
    const int r = blk*2 + half;
    er[half][c] = emb[r*DIM + c];
    __syncthreads();
    float acc = 0.f;
    #pragma unroll 8
    for (int k = 0; k < DIM; ++k) acc = fmaf(er[half][k], W1[k*DIM + c], acc);
    embW1[r*DIM + c] = f2bf(acc);
  } else if (blk < 448) {
    int idx = (blk - 256)*256 + tid;               // 49152 total
    int s = idx >> 14, rem = idx & 16383;
    int ks = rem >> 12, n = (rem >> 9) & 7, lane = (rem >> 3) & 63, j = rem & 7;
    int lg = lane >> 4, l15 = lane & 15;
    int k = ks*32 + lg*8 + j, c = n*16 + l15;
    const float* src = (s == 0) ? W2 : ((s == 1) ? P1 : P2);
    wswz[idx] = f2bf(src[k*DIM + c]);
  } else {
    cnt[(blk - 448)*256 + tid] = 0;                // 512 blocks -> 131072
  }
}

// ------- edge scatter, dst-range partitioned (XCD-local atomics/stores) ----
__global__ __launch_bounds__(256) void k_edges(const int* __restrict__ ei,
                                               const int* __restrict__ nf,
                                               int* __restrict__ cnt,
                                               unsigned short* __restrict__ slots){
  const int base = (blockIdx.x >> 3)*4096 + threadIdx.x;
  const int r    = blockIdx.x & 7;
  #pragma unroll
  for (int it = 0; it < 16; ++it) {
    const int e = base + it*256;
    const int d = ei[NEDGE + e];
    if ((d >> 14) == r) {
      const int s = ei[e];
      const int v = nf[s];
      const int pos = atomicAdd(&cnt[d], 1);
      if (pos < CAP) slots[(size_t)d*CAP + pos] = (unsigned short)v;
    }
  }
}

// ---- mega kernel: one block per batch, 1024 threads (16 waves/CU).
__global__ __launch_bounds__(1024, 1) void k_mega(
    const unsigned short* __restrict__ embW1, const int* __restrict__ nf,
    const int* __restrict__ cnt, const unsigned short* __restrict__ slots,
    const float* __restrict__ b1, const float* __restrict__ g1,
    const float* __restrict__ be1,
    const unsigned short* __restrict__ wswz,   // [3][4ks][8n][64lane][8j]
    const float* __restrict__ b2,  const float* __restrict__ pb1, const float* __restrict__ pb2,
    const float* __restrict__ ng,  const float* __restrict__ nbv,
    const float* __restrict__ eW1, const float* __restrict__ eb1,
    const float* __restrict__ eg,  const float* __restrict__ ebe,
    const float* __restrict__ eW2, const float* __restrict__ eb2,
    float* __restrict__ out)
{
  __shared__ unsigned short X[512][136];   // 139264 B
  __shared__ float gpart[16][128];
  __shared__ float mrow[128];
  __shared__ int   tq;
  const int tid   = threadIdx.x;
  const int bb    = blockIdx.x;            // batch index
  const int nbase = bb * NNODES;
  if (tid == 0) tq = 0;

  // ---------------- gather phase: 8 passes x 64 nodes ----------------
  {
    const int part = tid & 15;
    const short8* base8 = (const short8*)embW1;
    #pragma unroll 1
    for (int pass = 0; pass < 8; ++pass) {
      const int lnode = pass*64 + (tid >> 4);
      const int node  = nbase + lnode;
      const int self = nf[node];
      int m = cnt[node]; if (m > CAP) m = CAP;
      const unsigned short* sl = slots + (size_t)node*CAP;
      const uint4 sv0 = *(const uint4*)(sl);
      const uint4 sv1 = *(const uint4*)(sl + 8);
      const uint4 sv2 = *(const uint4*)(sl + 16);
      unsigned sw[12] = {sv0.x,sv0.y,sv0.z,sv0.w, sv1.x,sv1.y,sv1.z,sv1.w,
                         sv2.x,sv2.y,sv2.z,sv2.w};
      float a[8];
      {
        const float4* bp = (const float4*)(b1 + part*8);
        float4 x = bp[0], y = bp[1];
        a[0]=x.x; a[1]=x.y; a[2]=x.z; a[3]=x.w;
        a[4]=y.x; a[5]=y.y; a[6]=y.z; a[7]=y.w;
      }
#define ACC8(V) { _Pragma("unroll") \
      for (int i_ = 0; i_ < 8; ++i_) { \
        unsigned uu = ((unsigned)(unsigned short)(V)[i_]) << 16; \
        a[i_] += __builtin_bit_cast(float, uu); } }
      {
        short8 t0 = base8[(size_t)self*16 + part];
        short8 t[8];
        #pragma unroll
        for (int e = 0; e < 8; ++e) {
          unsigned id = (sw[e >> 1] >> ((e & 1)*16)) & 0xffffu;
          int idx = (e < m) ? (int)id : self;
          t[e] = base8[(size_t)idx*16 + part];
        }
        ACC8(t0)
        #pragma unroll
        for (int e = 0; e < 8; ++e) if (e < m) ACC8(t[e])
      }
      if (m > 8) {
        short8 t[8];
        #pragma unroll
        for (int e = 0; e < 8; ++e) {
          unsigned id = (sw[4 + (e >> 1)] >> ((e & 1)*16)) & 0xffffu;
          int idx = (e + 8 < m) ? (int)id : self;
          t[e] = base8[(size_t)idx*16 + part];
        }
        #pragma unroll
        for (int e = 0; e < 8; ++e) if (e + 8 < m) ACC8(t[e])
      }
      if (m > 16) {
        short8 t[8];
        #pragma unroll
        for (int e = 0; e < 8; ++e) {
          unsigned id = (sw[8 + (e >> 1)] >> ((e & 1)*16)) & 0xffffu;
          int idx = (e + 16 < m) ? (int)id : self;
          t[e] = base8[(size_t)idx*16 + part];
        }
        #pragma unroll
        for (int e = 0; e < 8; ++e) if (e + 16 < m) ACC8(t[e])
      }
      for (int e = 24; e < m; ++e) {
        short8 t = base8[(size_t)sl[e]*16 + part];
        ACC8(t)
      }
      float s = 0.f, qs = 0.f;
      #pragma unroll
      for (int i = 0; i < 8; ++i) { s += a[i]; qs += a[i]*a[i]; }
      #pragma unroll
      for (int msk = 1; msk < 16; msk <<= 1) {
        s  += __shfl_xor(s,  msk, 64);
        qs += __shfl_xor(qs, msk, 64);
      }
      const float mean = s * (1.f/128.f);
      const float var  = qs * (1.f/128.f) - mean*mean;
      const float rs   = rsqrtf(var + 1e-5f);
      const float4* gp = (const float4*)(g1  + part*8);
      const float4* ep = (const float4*)(be1 + part*8);
      float4 g0 = gp[0], g1v = gp[1], e0 = ep[0], e1v = ep[1];
      float gg[8] = {g0.x,g0.y,g0.z,g0.w, g1v.x,g1v.y,g1v.z,g1v.w};
      float eb[8] = {e0.x,e0.y,e0.z,e0.w, e1v.x,e1v.y,e1v.z,e1v.w};
      float v[8];
      #pragma unroll
      for (int i = 0; i < 8; ++i)
        v[i] = fmaxf((a[i] - mean)*rs*gg[i] + eb[i], 0.f);
      uint4 pk;
      pk.x = (unsigned)f2bf(v[0]) | ((unsigned)f2bf(v[1]) << 16);
      pk.y = (unsigned)f2bf(v[2]) | ((unsigned)f2bf(v[3]) << 16);
      pk.z = (unsigned)f2bf(v[4]) | ((unsigned)f2bf(v[5]) << 16);
      pk.w = (unsigned)f2bf(v[6]) | ((unsigned)f2bf(v[7]) << 16);
      *(uint4*)&X[lnode][part*8] = pk;
    }
  }
  __syncthreads();

  // ------------- MLP phase: 16 waves, wave-private rows, no barriers -------
  const int wave = tid >> 6, lane = tid & 63;
  const int l15 = lane & 15, lg = lane >> 4;
  const short8* ws8 = (const short8*)wswz;
  const float PRESCL = 0.29730177875068026f;   // 128^-0.25; (PRESCL^2 = 1/sqrt(128))
  float pc[8];
  #pragma unroll
  for (int n = 0; n < 8; ++n) pc[n] = 0.f;

  #pragma unroll
  for (int s = 0; s < 3; ++s) {
    f32x4 acc[2][8];
    #pragma unroll
    for (int p2 = 0; p2 < 2; ++p2)
      #pragma unroll
      for (int n = 0; n < 8; ++n) acc[p2][n] = (f32x4){0.f,0.f,0.f,0.f};
    #pragma unroll
    for (int ks = 0; ks < 4; ++ks) {
      short8 bf[8];
      #pragma unroll
      for (int n = 0; n < 8; ++n) bf[n] = ws8[s*2048 + ks*512 + n*64 + lane];
      #pragma unroll
      for (int p2 = 0; p2 < 2; ++p2) {
        short8 af = *(const short8*)&X[p2*256 + wave*16 + l15][ks*32 + lg*8];
        #pragma unroll
        for (int n = 0; n < 8; ++n)
          acc[p2][n] = __builtin_amdgcn_mfma_f32_16x16x32_bf16(af, bf[n], acc[p2][n], 0, 0, 0);
      }
    }
    if (s < 2) {
      const float* bias = (s == 0) ? b2 : pb1;
      float bv[8];
      #pragma unroll
      for (int n = 0; n < 8; ++n) bv[n] = bias[n*16 + l15];
      #pragma unroll
      for (int p2 = 0; p2 < 2; ++p2)
        #pragma unroll
        for (int n = 0; n < 8; ++n)
          #pragma unroll
          for (int q = 0; q < 4; ++q) {
            float v = acc[p2][n][q] + bv[n];
            if (s == 1) v = fmaxf(v, 0.f);
            X[p2*256 + wave*16 + lg*4 + q][n*16 + l15] = f2bf(v);
          }
      // same-wave LDS RAW: in-order ds pipeline; no barrier needed
    } else {
      float bv[8], gc[8], bc[8];
      #pragma unroll
      for (int n = 0; n < 8; ++n) {
        bv[n] = pb2[n*16 + l15];
        gc[n] = ng [n*16 + l15];
        bc[n] = nbv[n*16 + l15];
      }
      #pragma unroll
      for (int p2 = 0; p2 < 2; ++p2) {
        float sr[4] = {0,0,0,0}, qr[4] = {0,0,0,0};
        #pragma unroll
        for (int n = 0; n < 8; ++n)
          #pragma unroll
          for (int q = 0; q < 4; ++q) {
            float v = acc[p2][n][q] + bv[n];
            acc[p2][n][q] = v;
            sr[q] += v; qr[q] += v*v;
          }
        #pragma unroll
        for (int msk = 1; msk < 16; msk <<= 1)
          #pragma unroll
          for (int q = 0; q < 4; ++q) {
            sr[q] += __shfl_xor(sr[q], msk, 64);
            qr[q] += __shfl_xor(qr[q], msk, 64);
          }
        float mean[4], rs[4];
        #pragma unroll
        for (int q = 0; q < 4; ++q) {
          mean[q] = sr[q]*(1.f/128.f);
          float var = qr[q]*(1.f/128.f) - mean[q]*mean[q];
          rs[q] = rsqrtf(var + 1e-5f);
        }
        #pragma unroll
        for (int n = 0; n < 8; ++n)
          #pragma unroll
          for (int q = 0; q < 4; ++q) {
            float xo = (acc[p2][n][q] - mean[q])*rs[q]*gc[n] + bc[n];
            X[p2*256 + wave*16 + lg*4 + q][n*16 + l15] = f2bf(xo * PRESCL);
            pc[n] += xo;
          }
      }
    }
  }
  // column partials: reduce over lg, store per wave
  #pragma unroll
  for (int n = 0; n < 8; ++n) {
    pc[n] += __shfl_xor(pc[n], 16, 64);
    pc[n] += __shfl_xor(pc[n], 32, 64);
  }
  if (lg == 0) {
    #pragma unroll
    for (int n = 0; n < 8; ++n) gpart[wave][n*16 + l15] = pc[n];
  }
  __syncthreads();   // X fully written (pre-scaled), gpart ready

  // ---------------- exit MLP: wave 0 solo, barrier-free ----------------
  if (wave == 0) {
    const int c0 = lane, c1 = lane + 64;
    float m0 = 0.f, m1 = 0.f;
    #pragma unroll
    for (int w = 0; w < 16; ++w) { m0 += gpart[w][c0]; m1 += gpart[w][c1]; }
    mrow[c0] = m0 * (1.f/512.f);
    mrow[c1] = m1 * (1.f/512.f);
    float u0 = eb1[c0], u1 = eb1[c1];
    #pragma unroll 8
    for (int k = 0; k < DIM; ++k) {
      const float mk = mrow[k];
      u0 = fmaf(mk, eW1[k*DIM + c0], u0);
      u1 = fmaf(mk, eW1[k*DIM + c1], u1);
    }
    float s2 = u0 + u1, q2 = u0*u0 + u1*u1;
    #pragma unroll
    for (int msk = 1; msk < 64; msk <<= 1) {
      s2 += __shfl_xor(s2, msk, 64); q2 += __shfl_xor(q2, msk, 64);
    }
    const float mean = s2*(1.f/128.f);
    const float var  = q2*(1.f/128.f) - mean*mean;
    const float rs   = rsqrtf(var + 1e-5f);
    float a0 = fmaxf((u0 - mean)*rs*eg[c0] + ebe[c0], 0.f);
    float a1 = fmaxf((u1 - mean)*rs*eg[c1] + ebe[c1], 0.f);
    float p = a0*eW2[c0] + a1*eW2[c1];
    #pragma unroll
    for (int msk = 1; msk < 64; msk <<= 1) p += __shfl_xor(p, msk, 64);
    if (lane == 0) {
      float e = p + eb2[0];
      out[bb*3 + 0] = 0.f;
      out[bb*3 + 1] = 1.f - e;
      out[bb*3 + 2] = e;
    }
  }
  if (wave == 1) {
    if (lane < 8)   out[768 + bb*8 + lane] = 0.f;   // edge_class
    if (lane == 8)  out[2816 + bb] = 0.f;           // node_class
  }

  // -------- scores phase: swapped-operand MFMA, float4 stores, task queue ---
  // task = (p, rg): B = Xi rows (gi = ti*128+rg*16+l15), A = Xj chunk n.
  // C layout: acc[n][q] = S[gj = tj*128+n*16+lg*4+q][gi]  -> 4 consecutive gj.
  float* ea = out + 3072 + (size_t)bb*EPB;
  for (;;) {
    int task = 0;
    if (lane == 0) task = atomicAdd(&tq, 1);
    task = __shfl(task, 0, 64);
    if (task >= 80) break;
    const int p  = task >> 3, rg = task & 7;
    const int ti = (int)((0x3221110000ULL >> (p*4)) & 0xF);
    const int tj = (int)((0x3323213210ULL >> (p*4)) & 0xF);
    const bool diag = (ti == tj);
    const int nlo = diag ? rg : 0;

    f32x4 acc[8];
    #pragma unroll
    for (int n = 0; n < 8; ++n) acc[n] = (f32x4){0,0,0,0};
    #pragma unroll
    for (int ks = 0; ks < 4; ++ks) {
      const int k0 = ks*32 + lg*8;
      short8 bfrag = *(const short8*)&X[ti*128 + rg*16 + l15][k0];   // B = Xi
      #pragma unroll
      for (int n = 0; n < 8; ++n) {
        if (n >= nlo) {
          short8 afrag = *(const short8*)&X[tj*128 + n*16 + l15][k0]; // A = Xj
          acc[n] = __builtin_amdgcn_mfma_f32_16x16x32_bf16(afrag, bfrag, acc[n], 0, 0, 0);
        }
      }
    }
    const int lgi = rg*16 + l15;
    const int gi  = ti*128 + lgi;
    const int rowbase = gi*511 - ((gi*(gi-1)) >> 1) - gi - 1;
    float* rowp = ea + rowbase + tj*128;
    #pragma unroll
    for (int n = 0; n < 8; ++n) {
      if (n < nlo) continue;
      const int lgj = n*16 + lg*4;
      float4 v = make_float4(acc[n][0], acc[n][1], acc[n][2], acc[n][3]);
      if (!diag || lgj > lgi) {
        *(float4*)(rowp + lgj) = v;
      } else if (lgj + 3 > lgi) {
        #pragma unroll
        for (int j = 1; j < 4; ++j)
          if (lgj + j > lgi) rowp[lgj + j] = acc[n][j];
      }
    }
  }
}

extern "C" void kernel_launch(void* const* d_in, const int* in_sizes, int n_in,
                              void* d_out, int out_size, void* d_ws, size_t ws_size,
                              hipStream_t stream) {
  const int*   nf   = (const int*)d_in[0];
  const int*   ei   = (const int*)d_in[1];
  const float* emb  = (const float*)d_in[3];
  const float* gW1  = (const float*)d_in[4];
  const float* gb1  = (const float*)d_in[5];
  const float* gg1  = (const float*)d_in[6];
  const float* gbe1 = (const float*)d_in[7];
  const float* gW2  = (const float*)d_in[8];
  const float* gb2  = (const float*)d_in[9];
  const float* pW1  = (const float*)d_in[10];
  const float* pb1  = (const float*)d_in[11];
  const float* pW2  = (const float*)d_in[12];
  const float* pb2  = (const float*)d_in[13];
  const float* ng   = (const float*)d_in[14];
  const float* nb   = (const float*)d_in[15];
  const float* eW1  = (const float*)d_in[16];
  const float* eb1  = (const float*)d_in[17];
  const float* eg   = (const float*)d_in[18];
  const float* ebe  = (const float*)d_in[19];
  const float* eW2  = (const float*)d_in[20];
  const float* eb2  = (const float*)d_in[21];
  float* out = (float*)d_out;

  char* ws = (char*)d_ws;
  unsigned short* embW1 = (unsigned short*)ws;                 // 131072 B used
  unsigned short* wswz  = (unsigned short*)(ws + 262144);      // 98304 B
  int*            cnt   = (int*)(ws + 360448);                 // 524288 B
  unsigned short* slots = (unsigned short*)(ws + 884736);      // 8388608 B (CAP=32)
  if (ws_size < 9273344) return;

  k_prep  <<<960,  256, 0, stream>>>(emb, gW1, embW1, gW2, pW1, pW2, wswz, cnt);
  k_edges <<<2048, 256, 0, stream>>>(ei, nf, cnt, slots);
  k_mega  <<<256, 1024, 0, stream>>>(embW1, nf, cnt, slots, gb1, gg1, gbe1,
                                     wswz, gb2, pb1, pb2, ng, nb,
                                     eW1, eb1, eg, ebe, eW2, eb2, out);
}